// Round 7
// baseline (387.674 us; speedup 1.0000x reference)
//
#include <hip/hip_runtime.h>
#include <math.h>

#define N_ATOMS 20000
#define G_GRAPHS 500
#define NPG 40
#define DEG 16
#define E_EDGES (N_ATOMS * DEG)
#define EPM (NPG * DEG)          // 640 edges per molecule
#define HID 128
#define NF 128
#define TBL2 160                 // cubic-interp table grid points
#define TROWS (TBL2 + 2)         // +1 extrapolated row each end (Catmull-Rom)
#define CUTOFF 10.0f
#define LOG2F_ 0.6931471805599453f
#define LTHR 1024

__device__ __forceinline__ float ssp_f(float x) {
  float ax = fabsf(x);
  return fmaxf(x, 0.0f) + log1pf(expf(-ax)) - LOG2F_;
}

// ---------------- embedding gather ----------------
__global__ void k_embed(const float* __restrict__ emb, const int* __restrict__ z,
                        float* __restrict__ h) {
  int t = blockIdx.x * blockDim.x + threadIdx.x;
  if (t >= N_ATOMS * HID) return;
  int i = t >> 7, c = t & 127;
  h[t] = emb[z[i] * HID + c];
}

// ---- filter tables (all 3 layers); stored row s = grid row s-1, d=(s-1)*h ----
__global__ void k_table(const float* __restrict__ w1_, const float* __restrict__ b1_,
                        const float* __restrict__ w2_, const float* __restrict__ b2_,
                        float* __restrict__ table_) {
  __shared__ float ea[16][NF];
  __shared__ float hidv[16][NF];
  int l = blockIdx.y;
  const float* w1 = w1_ + (size_t)l * NF * NF;
  const float* b1 = b1_ + (size_t)l * NF;
  const float* w2 = w2_ + (size_t)l * NF * NF;
  const float* b2 = b2_ + (size_t)l * NF;
  float* table = table_ + (size_t)l * TROWS * NF;
  int j = threadIdx.x;
  int rbase = blockIdx.x * 16;
  const float h = CUTOFF / (float)(TBL2 - 1);
  const float delta = CUTOFF / (float)(NF - 1);
  const float coeff = -0.5f / (delta * delta);
#pragma unroll
  for (int rr = 0; rr < 16; ++rr) {
    float d = ((float)(rbase + rr) - 1.0f) * h;
    float t = d - delta * (float)j;
    ea[rr][j] = expf(coeff * t * t);
  }
  __syncthreads();
  float b1j = b1[j];
  float acc[16];
#pragma unroll
  for (int rr = 0; rr < 16; ++rr) acc[rr] = b1j;
  for (int k = 0; k < NF; ++k) {
    float wv = w1[k * NF + j];
#pragma unroll
    for (int rr = 0; rr < 16; ++rr) acc[rr] = fmaf(ea[rr][k], wv, acc[rr]);
  }
#pragma unroll
  for (int rr = 0; rr < 16; ++rr) hidv[rr][j] = ssp_f(acc[rr]);
  __syncthreads();
  float b2j = b2[j];
#pragma unroll
  for (int rr = 0; rr < 16; ++rr) acc[rr] = b2j;
  for (int k = 0; k < NF; ++k) {
    float wv = w2[k * NF + j];
#pragma unroll
    for (int rr = 0; rr < 16; ++rr) acc[rr] = fmaf(hidv[rr][k], wv, acc[rr]);
  }
#pragma unroll
  for (int rr = 0; rr < 16; ++rr) {
    int s = rbase + rr;
    if (s < TROWS) {
      float d = ((float)s - 1.0f) * h;
      float C = 0.5f * (cosf(d * (float)M_PI / CUTOFF) + 1.0f);
      table[(size_t)s * NF + j] = acc[rr] * C;
    }
  }
}

// ---- one-time: distances + CSR-by-destination (deterministic, parallel fill) ----
// pack per edge: row 6b | i0 8b | frac 18b
__global__ void k_csr(const float* __restrict__ pos, const int* __restrict__ ei,
                      unsigned* __restrict__ ginfo, int* __restrict__ gstart) {
  __shared__ float spos[NPG * 3];
  __shared__ int cnt[NPG];
  __shared__ int pfx[NPG + 1];
  __shared__ unsigned epk[EPM];
  __shared__ unsigned char ecol[EPM];
  __shared__ unsigned ssort[EPM];
  int g = blockIdx.x;
  int a0 = g * NPG;
  int t = threadIdx.x;  // 64 threads
  for (int i = t; i < NPG * 3; i += 64) spos[i] = pos[a0 * 3 + i];
  if (t < NPG) cnt[t] = 0;
  __syncthreads();
  int ebase = a0 * DEG;
  const float tscale = (float)(TBL2 - 1) / CUTOFF;
  for (int i = t; i < EPM; i += 64) {
    int r = ei[ebase + i] - a0;
    int c = ei[E_EDGES + ebase + i] - a0;
    float dx = spos[3 * r + 0] - spos[3 * c + 0];
    float dy = spos[3 * r + 1] - spos[3 * c + 1];
    float dz = spos[3 * r + 2] - spos[3 * c + 2];
    float ft = sqrtf(dx * dx + dy * dy + dz * dz) * tscale;
    int i0 = min((int)ft, TBL2 - 2);
    float tt = ft - (float)i0;
    unsigned ttf = (unsigned)(tt * 262144.0f);
    if (ttf > 262143u) ttf = 262143u;
    epk[i] = ((unsigned)r << 26) | ((unsigned)i0 << 18) | ttf;
    ecol[i] = (unsigned char)c;
    atomicAdd(&cnt[c], 1);
  }
  __syncthreads();
  if (t == 0) {
    int s = 0;
    for (int a = 0; a < NPG; ++a) { pfx[a] = s; s += cnt[a]; }
    pfx[NPG] = s;
  }
  __syncthreads();
  // lane-per-atom order-preserving fill (broadcast LDS reads)
  if (t < NPG) {
    int p = pfx[t];
    for (int e = 0; e < EPM; ++e) {
      unsigned pk = epk[e];   // broadcast
      if ((int)ecol[e] == t) ssort[p++] = pk;
    }
  }
  __syncthreads();
  for (int i = t; i < EPM; i += 64) ginfo[(size_t)g * EPM + i] = ssort[i];
  if (t < NPG) gstart[g * NPG + t] = pfx[t];
}

// ---------------- fused per-molecule layer (1024 threads, 16 waves) ----------------
__global__ void __launch_bounds__(LTHR) k_layer(
    float* __restrict__ hbuf, const unsigned* __restrict__ ginfo,
    const int* __restrict__ gstart, const float* __restrict__ tbl,
    const float* __restrict__ w1, const float* __restrict__ w2,
    const float* __restrict__ b2, const float* __restrict__ lw,
    const float* __restrict__ lb) {
  __shared__ float sh[NPG][HID];   // 20,480 B : h (residual kept)
  __shared__ float sb[NPG][HID];   // 20,480 B : x1, then u
  __shared__ float sg[NPG][HID];   // 20,480 B : agg
  __shared__ unsigned smeta[EPM];  //  2,560 B
  __shared__ int sstart[NPG + 1];
  int g = blockIdx.x;
  int a0 = g * NPG;
  int t = threadIdx.x;

  {
    const float4* hin = (const float4*)(hbuf + (size_t)a0 * HID);
    float4* sh4 = (float4*)sh;
    for (int i = t; i < NPG * HID / 4; i += LTHR) sh4[i] = hin[i];
    const unsigned* gin = ginfo + (size_t)g * EPM;
    for (int i = t; i < EPM; i += LTHR) smeta[i] = gin[i];
    if (t < NPG) sstart[t] = gstart[g * NPG + t];
    if (t == 0) sstart[NPG] = EPM;
  }
  __syncthreads();

  int j = t & 127, ar = t >> 7;  // ar in 0..7; rows ar+8m, m=0..4

  // ---- x1 = sh @ w1 -> sb ----
  {
    float acc[5];
#pragma unroll
    for (int m = 0; m < 5; ++m) acc[m] = 0.f;
    for (int k = 0; k < HID; k += 4) {
      float wa = w1[(k + 0) * NF + j];
      float wb = w1[(k + 1) * NF + j];
      float wc = w1[(k + 2) * NF + j];
      float wd = w1[(k + 3) * NF + j];
#pragma unroll
      for (int m = 0; m < 5; ++m) {
        float4 hv = *(const float4*)&sh[ar + 8 * m][k];
        acc[m] = fmaf(hv.x, wa, acc[m]);
        acc[m] = fmaf(hv.y, wb, acc[m]);
        acc[m] = fmaf(hv.z, wc, acc[m]);
        acc[m] = fmaf(hv.w, wd, acc[m]);
      }
    }
#pragma unroll
    for (int m = 0; m < 5; ++m) sb[ar + 8 * m][j] = acc[m];
  }
  __syncthreads();

  // ---- edge aggregation: wave owns atoms wave, wave+16, ... ----
  {
    int wave = t >> 6, lane = t & 63;
    const float2* sb2 = (const float2*)sb;
    for (int a = wave; a < NPG; a += 16) {
      int kb = sstart[a], ke = sstart[a + 1];
      float accx = 0.f, accy = 0.f;
      int k = kb;
      for (; k + 1 < ke; k += 2) {
        unsigned m0 = smeta[k], m1 = smeta[k + 1];
        int r0 = m0 >> 26, r1 = m1 >> 26;
        int i00 = (m0 >> 18) & 255, i01 = (m1 >> 18) & 255;
        float t0 = (float)(m0 & 262143u) * (1.0f / 262144.0f);
        float t1 = (float)(m1 & 262143u) * (1.0f / 262144.0f);
        const float2* b0 = (const float2*)(tbl + (size_t)i00 * NF) + lane;
        const float2* b1 = (const float2*)(tbl + (size_t)i01 * NF) + lane;
        float2 p00 = b0[0], p01 = b0[64], p02 = b0[128], p03 = b0[192];
        float2 p10 = b1[0], p11 = b1[64], p12 = b1[128], p13 = b1[192];
        float2 xa = sb2[r0 * 64 + lane];
        float2 xb = sb2[r1 * 64 + lane];
        float q2 = t0 * t0, q3 = q2 * t0;
        float w0 = 0.5f * (-q3 + 2.f * q2 - t0);
        float w1_ = 0.5f * (3.f * q3 - 5.f * q2 + 2.f);
        float w2_ = 0.5f * (-3.f * q3 + 4.f * q2 + t0);
        float w3 = 0.5f * (q3 - q2);
        float fx = w0 * p00.x; fx = fmaf(w1_, p01.x, fx); fx = fmaf(w2_, p02.x, fx); fx = fmaf(w3, p03.x, fx);
        float fy = w0 * p00.y; fy = fmaf(w1_, p01.y, fy); fy = fmaf(w2_, p02.y, fy); fy = fmaf(w3, p03.y, fy);
        float s2 = t1 * t1, s3 = s2 * t1;
        float v0 = 0.5f * (-s3 + 2.f * s2 - t1);
        float v1 = 0.5f * (3.f * s3 - 5.f * s2 + 2.f);
        float v2 = 0.5f * (-3.f * s3 + 4.f * s2 + t1);
        float v3 = 0.5f * (s3 - s2);
        float gx = v0 * p10.x; gx = fmaf(v1, p11.x, gx); gx = fmaf(v2, p12.x, gx); gx = fmaf(v3, p13.x, gx);
        float gy = v0 * p10.y; gy = fmaf(v1, p11.y, gy); gy = fmaf(v2, p12.y, gy); gy = fmaf(v3, p13.y, gy);
        accx = fmaf(xa.x, fx, accx); accy = fmaf(xa.y, fy, accy);
        accx = fmaf(xb.x, gx, accx); accy = fmaf(xb.y, gy, accy);
      }
      if (k < ke) {
        unsigned m0 = smeta[k];
        int r0 = m0 >> 26;
        int i00 = (m0 >> 18) & 255;
        float t0 = (float)(m0 & 262143u) * (1.0f / 262144.0f);
        const float2* b0 = (const float2*)(tbl + (size_t)i00 * NF) + lane;
        float2 p00 = b0[0], p01 = b0[64], p02 = b0[128], p03 = b0[192];
        float2 xa = sb2[r0 * 64 + lane];
        float q2 = t0 * t0, q3 = q2 * t0;
        float w0 = 0.5f * (-q3 + 2.f * q2 - t0);
        float w1_ = 0.5f * (3.f * q3 - 5.f * q2 + 2.f);
        float w2_ = 0.5f * (-3.f * q3 + 4.f * q2 + t0);
        float w3 = 0.5f * (q3 - q2);
        float fx = w0 * p00.x; fx = fmaf(w1_, p01.x, fx); fx = fmaf(w2_, p02.x, fx); fx = fmaf(w3, p03.x, fx);
        float fy = w0 * p00.y; fy = fmaf(w1_, p01.y, fy); fy = fmaf(w2_, p02.y, fy); fy = fmaf(w3, p03.y, fy);
        accx = fmaf(xa.x, fx, accx); accy = fmaf(xa.y, fy, accy);
      }
      ((float2*)sg[a])[lane] = make_float2(accx, accy);
    }
  }
  __syncthreads();

  // ---- s = ssp(sg @ w2 + b2) -> sb ----
  {
    float bj = b2[j];
    float acc[5];
#pragma unroll
    for (int m = 0; m < 5; ++m) acc[m] = bj;
    for (int k = 0; k < NF; k += 4) {
      float wa = w2[(k + 0) * HID + j];
      float wb = w2[(k + 1) * HID + j];
      float wc = w2[(k + 2) * HID + j];
      float wd = w2[(k + 3) * HID + j];
#pragma unroll
      for (int m = 0; m < 5; ++m) {
        float4 gv = *(const float4*)&sg[ar + 8 * m][k];
        acc[m] = fmaf(gv.x, wa, acc[m]);
        acc[m] = fmaf(gv.y, wb, acc[m]);
        acc[m] = fmaf(gv.z, wc, acc[m]);
        acc[m] = fmaf(gv.w, wd, acc[m]);
      }
    }
#pragma unroll
    for (int m = 0; m < 5; ++m) sb[ar + 8 * m][j] = ssp_f(acc[m]);
  }
  __syncthreads();

  // ---- x = sb @ lw + lb; h += x (global write) ----
  {
    float bj = lb[j];
    float acc[5];
#pragma unroll
    for (int m = 0; m < 5; ++m) acc[m] = bj;
    for (int k = 0; k < HID; k += 4) {
      float wa = lw[(k + 0) * HID + j];
      float wb = lw[(k + 1) * HID + j];
      float wc = lw[(k + 2) * HID + j];
      float wd = lw[(k + 3) * HID + j];
#pragma unroll
      for (int m = 0; m < 5; ++m) {
        float4 uv = *(const float4*)&sb[ar + 8 * m][k];
        acc[m] = fmaf(uv.x, wa, acc[m]);
        acc[m] = fmaf(uv.y, wb, acc[m]);
        acc[m] = fmaf(uv.z, wc, acc[m]);
        acc[m] = fmaf(uv.w, wd, acc[m]);
      }
    }
#pragma unroll
    for (int m = 0; m < 5; ++m) {
      int a = ar + 8 * m;
      hbuf[(size_t)(a0 + a) * HID + j] = sh[a][j] + acc[m];
    }
  }
}

// ---------------- head ----------------
__global__ void k_head(const float* __restrict__ h, const float* __restrict__ hw1,
                       const float* __restrict__ hb1, const float* __restrict__ hw2,
                       const float* __restrict__ hb2, const int* __restrict__ batch,
                       float* __restrict__ out) {
  __shared__ float hs[4][HID];
  int i0 = blockIdx.x * 4;
  int j = threadIdx.x;  // 0..63
  for (int idx = j; idx < 4 * HID; idx += 64) hs[idx >> 7][idx & 127] = h[(size_t)i0 * HID + idx];
  __syncthreads();
  float bj = hb1[j];
  float acc[4];
#pragma unroll
  for (int m = 0; m < 4; ++m) acc[m] = bj;
  for (int k = 0; k < HID; ++k) {
    float wv = hw1[k * 64 + j];
#pragma unroll
    for (int m = 0; m < 4; ++m) acc[m] = fmaf(hs[m][k], wv, acc[m]);
  }
  float w2v = hw2[j];
  float b2v = hb2[0];
  float ysum = 0.f;
#pragma unroll
  for (int m = 0; m < 4; ++m) {
    float p = ssp_f(acc[m]) * w2v;
    for (int off = 32; off > 0; off >>= 1) p += __shfl_down(p, off);
    if (j == 0) ysum += p + b2v;
  }
  if (j == 0) atomicAdd(&out[batch[i0]], ysum);
}

extern "C" void kernel_launch(void* const* d_in, const int* in_sizes, int n_in,
                              void* d_out, int out_size, void* d_ws, size_t ws_size,
                              hipStream_t stream) {
  const float* pos    = (const float*)d_in[0];
  const float* emb    = (const float*)d_in[1];
  const float* mlp_w1 = (const float*)d_in[2];
  const float* mlp_b1 = (const float*)d_in[3];
  const float* mlp_w2 = (const float*)d_in[4];
  const float* mlp_b2 = (const float*)d_in[5];
  const float* cf_w1  = (const float*)d_in[6];
  const float* cf_w2  = (const float*)d_in[7];
  const float* cf_b2  = (const float*)d_in[8];
  const float* lin_w  = (const float*)d_in[9];
  const float* lin_b  = (const float*)d_in[10];
  const float* hw1    = (const float*)d_in[11];
  const float* hb1    = (const float*)d_in[12];
  const float* hw2    = (const float*)d_in[13];
  const float* hb2    = (const float*)d_in[14];
  const int*   z      = (const int*)d_in[15];
  const int*   batch  = (const int*)d_in[16];
  const int*   ei     = (const int*)d_in[17];

  float* ws = (float*)d_ws;
  float* h      = ws;                                      // N*HID
  float* tbl    = h + (size_t)N_ATOMS * HID;               // 3*TROWS*NF
  int*   gstart = (int*)(tbl + 3ull * TROWS * NF);         // G*NPG
  unsigned* ginfo = (unsigned*)(gstart + G_GRAPHS * NPG);  // E
  size_t need = ((size_t)N_ATOMS * HID + 3ull * TROWS * NF + G_GRAPHS * NPG + E_EDGES) * 4ull;
  if (ws_size < need) return;

  k_embed<<<(N_ATOMS * HID + 255) / 256, 256, 0, stream>>>(emb, z, h);
  k_table<<<dim3((TROWS + 15) / 16, 3), NF, 0, stream>>>(mlp_w1, mlp_b1, mlp_w2, mlp_b2, tbl);
  k_csr<<<G_GRAPHS, 64, 0, stream>>>(pos, ei, ginfo, gstart);
  for (int l = 0; l < 3; ++l) {
    k_layer<<<G_GRAPHS, LTHR, 0, stream>>>(h, ginfo, gstart, tbl + (size_t)l * TROWS * NF,
                                           cf_w1 + (size_t)l * HID * NF,
                                           cf_w2 + (size_t)l * NF * HID,
                                           cf_b2 + (size_t)l * HID,
                                           lin_w + (size_t)l * HID * HID,
                                           lin_b + (size_t)l * HID);
  }
  hipMemsetAsync(d_out, 0, G_GRAPHS * 4, stream);
  k_head<<<N_ATOMS / 4, 64, 0, stream>>>(h, hw1, hb1, hw2, hb2, batch, (float*)d_out);
}

// Round 8
// 257.536 us; speedup vs baseline: 1.5053x; 1.5053x over previous
//
#include <hip/hip_runtime.h>
#include <math.h>

#define N_ATOMS 20000
#define G_GRAPHS 500
#define NPG 40
#define DEG 16
#define E_EDGES (N_ATOMS * DEG)
#define EPM (NPG * DEG)
#define HID 128
#define NF 128
#define TBL2 160
#define TROWS (TBL2 + 2)
#define CUTOFF 10.0f
#define LOG2F_ 0.6931471805599453f

typedef __attribute__((ext_vector_type(8))) short short8v;
typedef __attribute__((ext_vector_type(4))) float f32x4;
typedef unsigned short ushort_t;

__device__ __forceinline__ float ssp_f(float x) {
  float ax = fabsf(x);
  return fmaxf(x, 0.0f) + log1pf(expf(-ax)) - LOG2F_;
}
__device__ __forceinline__ ushort_t bf16rne(float x) {
  unsigned u = __float_as_uint(x);
  unsigned r = 0x7FFFu + ((u >> 16) & 1u);
  return (ushort_t)((u + r) >> 16);
}
__device__ __forceinline__ unsigned pk2(float a, float b) {
  return (unsigned)bf16rne(a) | ((unsigned)bf16rne(b) << 16);
}
__device__ __forceinline__ float bflo(unsigned u) { return __uint_as_float(u << 16); }
__device__ __forceinline__ float bfhi(unsigned u) { return __uint_as_float(u & 0xFFFF0000u); }
// swizzled element index for bf16 [48][128] LDS buffers (kills stride-256B bank conflict)
__device__ __forceinline__ int bidx(int row, int col) {
  return row * 128 + (col ^ ((row & 7) << 3));
}

// ---------------- embedding gather ----------------
__global__ void k_embed(const float* __restrict__ emb, const int* __restrict__ z,
                        float* __restrict__ h) {
  int t = blockIdx.x * blockDim.x + threadIdx.x;
  if (t >= N_ATOMS * HID) return;
  int i = t >> 7, c = t & 127;
  h[t] = emb[z[i] * HID + c];
}

// ---- filter tables (3 layers) -> bf16 [TROWS][128]; stored row s = grid row s-1 ----
__global__ void k_table(const float* __restrict__ w1_, const float* __restrict__ b1_,
                        const float* __restrict__ w2_, const float* __restrict__ b2_,
                        ushort_t* __restrict__ table_) {
  __shared__ float ea[16][NF];
  __shared__ float hidv[16][NF];
  int l = blockIdx.y;
  const float* w1 = w1_ + (size_t)l * NF * NF;
  const float* b1 = b1_ + (size_t)l * NF;
  const float* w2 = w2_ + (size_t)l * NF * NF;
  const float* b2 = b2_ + (size_t)l * NF;
  ushort_t* table = table_ + (size_t)l * TROWS * NF;
  int j = threadIdx.x;
  int rbase = blockIdx.x * 16;
  const float h = CUTOFF / (float)(TBL2 - 1);
  const float delta = CUTOFF / (float)(NF - 1);
  const float coeff = -0.5f / (delta * delta);
#pragma unroll
  for (int rr = 0; rr < 16; ++rr) {
    float d = ((float)(rbase + rr) - 1.0f) * h;
    float t = d - delta * (float)j;
    ea[rr][j] = expf(coeff * t * t);
  }
  __syncthreads();
  float b1j = b1[j];
  float acc[16];
#pragma unroll
  for (int rr = 0; rr < 16; ++rr) acc[rr] = b1j;
  for (int k = 0; k < NF; ++k) {
    float wv = w1[k * NF + j];
#pragma unroll
    for (int rr = 0; rr < 16; ++rr) acc[rr] = fmaf(ea[rr][k], wv, acc[rr]);
  }
#pragma unroll
  for (int rr = 0; rr < 16; ++rr) hidv[rr][j] = ssp_f(acc[rr]);
  __syncthreads();
  float b2j = b2[j];
#pragma unroll
  for (int rr = 0; rr < 16; ++rr) acc[rr] = b2j;
  for (int k = 0; k < NF; ++k) {
    float wv = w2[k * NF + j];
#pragma unroll
    for (int rr = 0; rr < 16; ++rr) acc[rr] = fmaf(hidv[rr][k], wv, acc[rr]);
  }
#pragma unroll
  for (int rr = 0; rr < 16; ++rr) {
    int s = rbase + rr;
    if (s < TROWS) {
      float d = ((float)s - 1.0f) * h;
      float C = 0.5f * (cosf(d * (float)M_PI / CUTOFF) + 1.0f);
      table[(size_t)s * NF + j] = bf16rne(acc[rr] * C);
    }
  }
}

// ---- one-time: transpose + bf16 the 9 GEMV weight matrices: wt[m][j][k] = w[m][k][j] ----
__global__ void k_prep(const float* __restrict__ cf_w1, const float* __restrict__ cf_w2,
                       const float* __restrict__ lin_w, ushort_t* __restrict__ wtb) {
  __shared__ float tile[32][33];
  int m = blockIdx.x;  // 0..8
  int l = m / 3, ty = m % 3;
  const float* src = (ty == 0 ? cf_w1 : ty == 1 ? cf_w2 : lin_w) + (size_t)l * 128 * 128;
  ushort_t* dst = wtb + (size_t)m * 128 * 128;
  int t = threadIdx.x;       // 256
  int tr = t >> 5, tc = t & 31;
  for (int tj = 0; tj < 4; ++tj)
    for (int ti = 0; ti < 4; ++ti) {
      __syncthreads();
#pragma unroll
      for (int i = 0; i < 4; ++i) {
        int r = tr + i * 8;
        tile[r][tc] = src[(ti * 32 + r) * 128 + tj * 32 + tc];
      }
      __syncthreads();
#pragma unroll
      for (int i = 0; i < 4; ++i) {
        int r = tr + i * 8;
        dst[(tj * 32 + r) * 128 + ti * 32 + tc] = bf16rne(tile[tc][r]);
      }
    }
}

// ---- one-time: distances + CSR-by-destination (deterministic) ----
__global__ void k_csr(const float* __restrict__ pos, const int* __restrict__ ei,
                      unsigned* __restrict__ ginfo, int* __restrict__ gstart) {
  __shared__ float spos[NPG * 3];
  __shared__ int cnt[NPG];
  __shared__ int pfx[NPG + 1];
  __shared__ unsigned epk[EPM];
  __shared__ unsigned char ecol[EPM];
  __shared__ unsigned ssort[EPM];
  int g = blockIdx.x;
  int a0 = g * NPG;
  int t = threadIdx.x;  // 64
  for (int i = t; i < NPG * 3; i += 64) spos[i] = pos[a0 * 3 + i];
  if (t < NPG) cnt[t] = 0;
  __syncthreads();
  int ebase = a0 * DEG;
  const float tscale = (float)(TBL2 - 1) / CUTOFF;
  for (int i = t; i < EPM; i += 64) {
    int r = ei[ebase + i] - a0;
    int c = ei[E_EDGES + ebase + i] - a0;
    float dx = spos[3 * r + 0] - spos[3 * c + 0];
    float dy = spos[3 * r + 1] - spos[3 * c + 1];
    float dz = spos[3 * r + 2] - spos[3 * c + 2];
    float ft = sqrtf(dx * dx + dy * dy + dz * dz) * tscale;
    int i0 = min((int)ft, TBL2 - 2);
    float tt = ft - (float)i0;
    unsigned ttf = (unsigned)(tt * 262144.0f);
    if (ttf > 262143u) ttf = 262143u;
    epk[i] = ((unsigned)r << 26) | ((unsigned)i0 << 18) | ttf;
    ecol[i] = (unsigned char)c;
    atomicAdd(&cnt[c], 1);
  }
  __syncthreads();
  if (t == 0) {
    int s = 0;
    for (int a = 0; a < NPG; ++a) { pfx[a] = s; s += cnt[a]; }
    pfx[NPG] = s;
  }
  __syncthreads();
  if (t < NPG) {
    int p = pfx[t];
    for (int e = 0; e < EPM; ++e) {
      unsigned pk = epk[e];
      if ((int)ecol[e] == t) ssort[p++] = pk;
    }
  }
  __syncthreads();
  for (int i = t; i < EPM; i += 64) ginfo[(size_t)g * EPM + i] = ssort[i];
  if (t < NPG) gstart[g * NPG + t] = pfx[t];
}

// ---------------- fused per-molecule layer: MFMA GEMVs + LDS-table edge agg ----------------
__global__ void __launch_bounds__(512) k_layer(
    float* __restrict__ hbuf, const unsigned* __restrict__ ginfo,
    const int* __restrict__ gstart, const ushort_t* __restrict__ tblb,
    const ushort_t* __restrict__ w1t, const ushort_t* __restrict__ w2t,
    const ushort_t* __restrict__ lwt, const float* __restrict__ b2,
    const float* __restrict__ lb) {
  __shared__ ushort_t stab[TROWS * 128];  // 41,472 B  bf16 filter table
  __shared__ ushort_t sb0[48 * 128];      // 12,288 B  bf16 A-operand buf (h -> agg)
  __shared__ ushort_t sb1[48 * 128];      // 12,288 B  bf16 A-operand buf (x1 -> u)
  __shared__ unsigned smeta[EPM];         //  2,560 B
  __shared__ int sstart[NPG + 1];
  int g = blockIdx.x, a0 = g * NPG, t = threadIdx.x;

  // ---- stage ----
  {
    const uint4* ti4 = (const uint4*)tblb;
    uint4* st4 = (uint4*)stab;
    for (int i = t; i < TROWS * 128 / 8; i += 512) st4[i] = ti4[i];
    const float2* hin = (const float2*)(hbuf + (size_t)a0 * HID);
    unsigned* b0u = (unsigned*)sb0;
    unsigned* b1u = (unsigned*)sb1;
    for (int i = t; i < NPG * 64; i += 512) {
      int row = i >> 6, cp = (i & 63) * 2;
      float2 v = hin[i];
      b0u[bidx(row, cp) >> 1] = pk2(v.x, v.y);
    }
    for (int i = t; i < 8 * 64; i += 512) {
      int row = 40 + (i >> 6), cw = i & 63;
      b0u[row * 64 + cw] = 0u;
      b1u[row * 64 + cw] = 0u;
    }
    const unsigned* gin = ginfo + (size_t)g * EPM;
    for (int i = t; i < EPM; i += 512) smeta[i] = gin[i];
    if (t < NPG) sstart[t] = gstart[g * NPG + t];
    if (t == 0) sstart[NPG] = EPM;
  }
  __syncthreads();

  int w = t >> 6, l = t & 63;
  int r15 = l & 15, q = l >> 4;
  int colo = w * 16 + r15;  // this lane's output column (per wave N-tile)

  // ---- GEMV1: x1 = h @ w1  (sb0 -> sb1) ----
  {
    short8v bfr[4];
    const ushort_t* wp = w1t + (size_t)colo * 128 + q * 8;
#pragma unroll
    for (int ks = 0; ks < 4; ++ks) bfr[ks] = *(const short8v*)(wp + ks * 32);
#pragma unroll
    for (int mt = 0; mt < 3; ++mt) {
      f32x4 acc = (f32x4){0.f, 0.f, 0.f, 0.f};
#pragma unroll
      for (int ks = 0; ks < 4; ++ks) {
        short8v af = *(const short8v*)&sb0[bidx(mt * 16 + r15, ks * 32 + q * 8)];
        acc = __builtin_amdgcn_mfma_f32_16x16x32_bf16(af, bfr[ks], acc, 0, 0, 0);
      }
#pragma unroll
      for (int r = 0; r < 4; ++r) sb1[bidx(mt * 16 + q * 4 + r, colo)] = bf16rne(acc[r]);
    }
  }
  __syncthreads();

  // ---- edge aggregation: agg = scatter(x1[row]*cubic(table)) (sb1 -> sb0), owned, LDS-only ----
  {
    const unsigned* tab32 = (const unsigned*)stab;
    const unsigned* b1u = (const unsigned*)sb1;
    unsigned* b0u = (unsigned*)sb0;
    for (int a = w; a < NPG; a += 8) {
      int kb = sstart[a], ke = sstart[a + 1];
      float accx = 0.f, accy = 0.f;
      for (int k = kb; k < ke; ++k) {
        unsigned m0 = smeta[k];
        int r0 = m0 >> 26;
        int i00 = (m0 >> 18) & 255;
        float t0 = (float)(m0 & 262143u) * (1.0f / 262144.0f);
        int base = i00 * 64 + l;
        unsigned u0 = tab32[base];
        unsigned u1 = tab32[base + 64];
        unsigned u2 = tab32[base + 128];
        unsigned u3 = tab32[base + 192];
        unsigned xv = b1u[bidx(r0, 2 * l) >> 1];
        float q2 = t0 * t0, q3 = q2 * t0;
        float w0 = 0.5f * (-q3 + 2.f * q2 - t0);
        float w1 = 0.5f * (3.f * q3 - 5.f * q2 + 2.f);
        float w2 = 0.5f * (-3.f * q3 + 4.f * q2 + t0);
        float w3 = 0.5f * (q3 - q2);
        float fx = w0 * bflo(u0);
        fx = fmaf(w1, bflo(u1), fx);
        fx = fmaf(w2, bflo(u2), fx);
        fx = fmaf(w3, bflo(u3), fx);
        float fy = w0 * bfhi(u0);
        fy = fmaf(w1, bfhi(u1), fy);
        fy = fmaf(w2, bfhi(u2), fy);
        fy = fmaf(w3, bfhi(u3), fy);
        accx = fmaf(bflo(xv), fx, accx);
        accy = fmaf(bfhi(xv), fy, accy);
      }
      b0u[bidx(a, 2 * l) >> 1] = pk2(accx, accy);
    }
  }
  __syncthreads();

  // ---- GEMV2: u = ssp(agg @ w2 + b2)  (sb0 -> sb1) ----
  {
    float bc = b2[colo];
    short8v bfr[4];
    const ushort_t* wp = w2t + (size_t)colo * 128 + q * 8;
#pragma unroll
    for (int ks = 0; ks < 4; ++ks) bfr[ks] = *(const short8v*)(wp + ks * 32);
#pragma unroll
    for (int mt = 0; mt < 3; ++mt) {
      f32x4 acc = (f32x4){0.f, 0.f, 0.f, 0.f};
#pragma unroll
      for (int ks = 0; ks < 4; ++ks) {
        short8v af = *(const short8v*)&sb0[bidx(mt * 16 + r15, ks * 32 + q * 8)];
        acc = __builtin_amdgcn_mfma_f32_16x16x32_bf16(af, bfr[ks], acc, 0, 0, 0);
      }
#pragma unroll
      for (int r = 0; r < 4; ++r) {
        int row = mt * 16 + q * 4 + r;
        float v = (row < 40) ? ssp_f(acc[r] + bc) : 0.f;  // keep pad rows zero
        sb1[bidx(row, colo)] = bf16rne(v);
      }
    }
  }
  __syncthreads();

  // ---- GEMV3: h += u @ lw + lb  (sb1 -> global, fp32 residual) ----
  {
    float bc = lb[colo];
    short8v bfr[4];
    const ushort_t* wp = lwt + (size_t)colo * 128 + q * 8;
#pragma unroll
    for (int ks = 0; ks < 4; ++ks) bfr[ks] = *(const short8v*)(wp + ks * 32);
#pragma unroll
    for (int mt = 0; mt < 3; ++mt) {
      f32x4 acc = (f32x4){0.f, 0.f, 0.f, 0.f};
#pragma unroll
      for (int ks = 0; ks < 4; ++ks) {
        short8v af = *(const short8v*)&sb1[bidx(mt * 16 + r15, ks * 32 + q * 8)];
        acc = __builtin_amdgcn_mfma_f32_16x16x32_bf16(af, bfr[ks], acc, 0, 0, 0);
      }
#pragma unroll
      for (int r = 0; r < 4; ++r) {
        int row = mt * 16 + q * 4 + r;
        if (row < 40) {
          size_t gi = (size_t)(a0 + row) * HID + colo;
          hbuf[gi] += acc[r] + bc;
        }
      }
    }
  }
}

// ---------------- head ----------------
__global__ void k_head(const float* __restrict__ h, const float* __restrict__ hw1,
                       const float* __restrict__ hb1, const float* __restrict__ hw2,
                       const float* __restrict__ hb2, const int* __restrict__ batch,
                       float* __restrict__ out) {
  __shared__ float hs[4][HID];
  int i0 = blockIdx.x * 4;
  int j = threadIdx.x;  // 0..63
  for (int idx = j; idx < 4 * HID; idx += 64) hs[idx >> 7][idx & 127] = h[(size_t)i0 * HID + idx];
  __syncthreads();
  float bj = hb1[j];
  float acc[4];
#pragma unroll
  for (int m = 0; m < 4; ++m) acc[m] = bj;
  for (int k = 0; k < HID; ++k) {
    float wv = hw1[k * 64 + j];
#pragma unroll
    for (int m = 0; m < 4; ++m) acc[m] = fmaf(hs[m][k], wv, acc[m]);
  }
  float w2v = hw2[j];
  float b2v = hb2[0];
  float ysum = 0.f;
#pragma unroll
  for (int m = 0; m < 4; ++m) {
    float p = ssp_f(acc[m]) * w2v;
    for (int off = 32; off > 0; off >>= 1) p += __shfl_down(p, off);
    if (j == 0) ysum += p + b2v;
  }
  if (j == 0) atomicAdd(&out[batch[i0]], ysum);
}

extern "C" void kernel_launch(void* const* d_in, const int* in_sizes, int n_in,
                              void* d_out, int out_size, void* d_ws, size_t ws_size,
                              hipStream_t stream) {
  const float* pos    = (const float*)d_in[0];
  const float* emb    = (const float*)d_in[1];
  const float* mlp_w1 = (const float*)d_in[2];
  const float* mlp_b1 = (const float*)d_in[3];
  const float* mlp_w2 = (const float*)d_in[4];
  const float* mlp_b2 = (const float*)d_in[5];
  const float* cf_w1  = (const float*)d_in[6];
  const float* cf_w2  = (const float*)d_in[7];
  const float* cf_b2  = (const float*)d_in[8];
  const float* lin_w  = (const float*)d_in[9];
  const float* lin_b  = (const float*)d_in[10];
  const float* hw1    = (const float*)d_in[11];
  const float* hb1    = (const float*)d_in[12];
  const float* hw2    = (const float*)d_in[13];
  const float* hb2    = (const float*)d_in[14];
  const int*   z      = (const int*)d_in[15];
  const int*   batch  = (const int*)d_in[16];
  const int*   ei     = (const int*)d_in[17];

  float* ws = (float*)d_ws;
  float*    h      = ws;                                       // N*HID f32
  ushort_t* tblb   = (ushort_t*)(h + (size_t)N_ATOMS * HID);   // 3*TROWS*128 bf16
  ushort_t* wtb    = tblb + 3 * TROWS * 128;                   // 9*128*128 bf16
  int*      gstart = (int*)(wtb + 9 * 128 * 128);              // G*NPG
  unsigned* ginfo  = (unsigned*)(gstart + G_GRAPHS * NPG);     // E
  size_t need = (size_t)N_ATOMS * HID * 4 + (3ull * TROWS * 128 + 9ull * 128 * 128) * 2 +
                (size_t)G_GRAPHS * NPG * 4 + (size_t)E_EDGES * 4;
  if (ws_size < need) return;

  k_embed<<<(N_ATOMS * HID + 255) / 256, 256, 0, stream>>>(emb, z, h);
  k_table<<<dim3((TROWS + 15) / 16, 3), NF, 0, stream>>>(mlp_w1, mlp_b1, mlp_w2, mlp_b2, tblb);
  k_prep<<<9, 256, 0, stream>>>(cf_w1, cf_w2, lin_w, wtb);
  k_csr<<<G_GRAPHS, 64, 0, stream>>>(pos, ei, ginfo, gstart);
  for (int l = 0; l < 3; ++l) {
    k_layer<<<G_GRAPHS, 512, 0, stream>>>(h, ginfo, gstart,
                                          tblb + (size_t)l * TROWS * 128,
                                          wtb + (size_t)(l * 3 + 0) * 128 * 128,
                                          wtb + (size_t)(l * 3 + 1) * 128 * 128,
                                          wtb + (size_t)(l * 3 + 2) * 128 * 128,
                                          cf_b2 + (size_t)l * HID,
                                          lin_b + (size_t)l * HID);
  }
  hipMemsetAsync(d_out, 0, G_GRAPHS * 4, stream);
  k_head<<<N_ATOMS / 4, 64, 0, stream>>>(h, hw1, hb1, hw2, hb2, batch, (float*)d_out);
}

// Round 9
// 166.341 us; speedup vs baseline: 2.3306x; 1.5482x over previous
//
#include <hip/hip_runtime.h>
#include <math.h>

#define N_ATOMS 20000
#define G_GRAPHS 500
#define NPG 40
#define DEG 16
#define E_EDGES (N_ATOMS * DEG)
#define EPM (NPG * DEG)
#define HID 128
#define NF 128
#define TBL2 96
#define TROWS (TBL2 + 2)   // 98: +1 extrapolated row each end (Catmull-Rom)
#define CUTOFF 10.0f
#define LOG2F_ 0.6931471805599453f

typedef __attribute__((ext_vector_type(8))) short short8v;
typedef __attribute__((ext_vector_type(4))) float f32x4;
typedef unsigned short ushort_t;

__device__ __forceinline__ float ssp_f(float x) {
  float ax = fabsf(x);
  return fmaxf(x, 0.0f) + log1pf(expf(-ax)) - LOG2F_;
}
__device__ __forceinline__ ushort_t bf16rne(float x) {
  unsigned u = __float_as_uint(x);
  unsigned r = 0x7FFFu + ((u >> 16) & 1u);
  return (ushort_t)((u + r) >> 16);
}
__device__ __forceinline__ unsigned pk2(float a, float b) {
  return (unsigned)bf16rne(a) | ((unsigned)bf16rne(b) << 16);
}
__device__ __forceinline__ float bflo(unsigned u) { return __uint_as_float(u << 16); }
__device__ __forceinline__ float bfhi(unsigned u) { return __uint_as_float(u & 0xFFFF0000u); }
__device__ __forceinline__ int bidx(int row, int col) {
  return row * 128 + (col ^ ((row & 7) << 3));
}

// ---- filter tables (3 layers) -> bf16 [TROWS][128]; 8 rows/block, latency-pipelined ----
__global__ void k_table(const float* __restrict__ w1_, const float* __restrict__ b1_,
                        const float* __restrict__ w2_, const float* __restrict__ b2_,
                        ushort_t* __restrict__ table_) {
  __shared__ float eaT[NF][8];   // [k][row]
  __shared__ float hvT[NF][8];
  int l = blockIdx.y;
  const float* w1 = w1_ + (size_t)l * NF * NF;
  const float* b1 = b1_ + (size_t)l * NF;
  const float* w2 = w2_ + (size_t)l * NF * NF;
  const float* b2 = b2_ + (size_t)l * NF;
  ushort_t* table = table_ + (size_t)l * TROWS * NF;
  int j = threadIdx.x;  // 0..127
  int rbase = blockIdx.x * 8;
  const float hh = CUTOFF / (float)(TBL2 - 1);
  const float delta = CUTOFF / (float)(NF - 1);
  const float coeff = -0.5f / (delta * delta);
#pragma unroll
  for (int rr = 0; rr < 8; ++rr) {
    float d = ((float)(rbase + rr) - 1.0f) * hh;
    float tt = d - delta * (float)j;
    eaT[j][rr] = expf(coeff * tt * tt);
  }
  __syncthreads();
  float acc[8], wreg[16];
  float b1j = b1[j];
#pragma unroll
  for (int rr = 0; rr < 8; ++rr) acc[rr] = b1j;
  for (int kb = 0; kb < NF; kb += 16) {
#pragma unroll
    for (int i = 0; i < 16; ++i) wreg[i] = w1[(kb + i) * NF + j];
#pragma unroll
    for (int i = 0; i < 16; ++i) {
      float4 e0 = *(const float4*)&eaT[kb + i][0];
      float4 e1 = *(const float4*)&eaT[kb + i][4];
      float wv = wreg[i];
      acc[0] = fmaf(e0.x, wv, acc[0]); acc[1] = fmaf(e0.y, wv, acc[1]);
      acc[2] = fmaf(e0.z, wv, acc[2]); acc[3] = fmaf(e0.w, wv, acc[3]);
      acc[4] = fmaf(e1.x, wv, acc[4]); acc[5] = fmaf(e1.y, wv, acc[5]);
      acc[6] = fmaf(e1.z, wv, acc[6]); acc[7] = fmaf(e1.w, wv, acc[7]);
    }
  }
#pragma unroll
  for (int rr = 0; rr < 8; ++rr) hvT[j][rr] = ssp_f(acc[rr]);
  __syncthreads();
  float b2j = b2[j];
#pragma unroll
  for (int rr = 0; rr < 8; ++rr) acc[rr] = b2j;
  for (int kb = 0; kb < NF; kb += 16) {
#pragma unroll
    for (int i = 0; i < 16; ++i) wreg[i] = w2[(kb + i) * NF + j];
#pragma unroll
    for (int i = 0; i < 16; ++i) {
      float4 e0 = *(const float4*)&hvT[kb + i][0];
      float4 e1 = *(const float4*)&hvT[kb + i][4];
      float wv = wreg[i];
      acc[0] = fmaf(e0.x, wv, acc[0]); acc[1] = fmaf(e0.y, wv, acc[1]);
      acc[2] = fmaf(e0.z, wv, acc[2]); acc[3] = fmaf(e0.w, wv, acc[3]);
      acc[4] = fmaf(e1.x, wv, acc[4]); acc[5] = fmaf(e1.y, wv, acc[5]);
      acc[6] = fmaf(e1.z, wv, acc[6]); acc[7] = fmaf(e1.w, wv, acc[7]);
    }
  }
#pragma unroll
  for (int rr = 0; rr < 8; ++rr) {
    int s = rbase + rr;
    if (s < TROWS) {
      float d = ((float)s - 1.0f) * hh;
      float C = 0.5f * (cosf(d * (float)M_PI / CUTOFF) + 1.0f);
      table[(size_t)s * NF + j] = bf16rne(acc[rr] * C);
    }
  }
}

// ---- one-time: transpose + bf16 the 9 GEMV weights: wt[m][j][k] = w[m][k][j] ----
__global__ void k_prep(const float* __restrict__ cf_w1, const float* __restrict__ cf_w2,
                       const float* __restrict__ lin_w, ushort_t* __restrict__ wtb) {
  __shared__ float tile[32][33];
  int b = blockIdx.x;      // 36 blocks = 9 mats x 4 col-stripes
  int m = b >> 2, tj = b & 3;
  int l = m / 3, ty = m % 3;
  const float* src = (ty == 0 ? cf_w1 : ty == 1 ? cf_w2 : lin_w) + (size_t)l * 128 * 128;
  ushort_t* dst = wtb + (size_t)m * 128 * 128;
  int t = threadIdx.x;  // 256
  int tr = t >> 5, tc = t & 31;
  for (int ti = 0; ti < 4; ++ti) {
    __syncthreads();
#pragma unroll
    for (int i = 0; i < 4; ++i) {
      int r = tr + i * 8;
      tile[r][tc] = src[(ti * 32 + r) * 128 + tj * 32 + tc];
    }
    __syncthreads();
#pragma unroll
    for (int i = 0; i < 4; ++i) {
      int r = tr + i * 8;
      dst[(tj * 32 + r) * 128 + ti * 32 + tc] = bf16rne(tile[tc][r]);
    }
  }
}

// ---- one-time: distances + CSR-by-destination (deterministic, ballot fill) ----
__global__ void __launch_bounds__(512) k_csr(const float* __restrict__ pos,
                                             const int* __restrict__ ei,
                                             unsigned* __restrict__ ginfo,
                                             int* __restrict__ gstart) {
  __shared__ float spos[NPG * 3];
  __shared__ int cnt[NPG];
  __shared__ int pfx[NPG + 1];
  __shared__ unsigned epk[EPM];
  __shared__ unsigned char ecol[EPM];
  __shared__ unsigned ssort[EPM];
  int g = blockIdx.x, a0 = g * NPG, t = threadIdx.x;
  if (t < NPG * 3) spos[t] = pos[a0 * 3 + t];
  if (t < NPG) cnt[t] = 0;
  __syncthreads();
  int ebase = a0 * DEG;
  const float tscale = (float)(TBL2 - 1) / CUTOFF;
  for (int i = t; i < EPM; i += 512) {
    int r = ei[ebase + i] - a0;
    int c = ei[E_EDGES + ebase + i] - a0;
    float dx = spos[3 * r + 0] - spos[3 * c + 0];
    float dy = spos[3 * r + 1] - spos[3 * c + 1];
    float dz = spos[3 * r + 2] - spos[3 * c + 2];
    float ft = sqrtf(dx * dx + dy * dy + dz * dz) * tscale;
    int i0 = min((int)ft, TBL2 - 2);
    float tt = ft - (float)i0;
    unsigned ttf = (unsigned)(tt * 262144.0f);
    if (ttf > 262143u) ttf = 262143u;
    epk[i] = ((unsigned)r << 26) | ((unsigned)i0 << 18) | ttf;
    ecol[i] = (unsigned char)c;
    atomicAdd(&cnt[c], 1);
  }
  __syncthreads();
  if (t == 0) {
    int s = 0;
    for (int a = 0; a < NPG; ++a) { pfx[a] = s; s += cnt[a]; }
    pfx[NPG] = s;
  }
  __syncthreads();
  int w = t >> 6, lane = t & 63;
  for (int a = w * 5; a < w * 5 + 5; ++a) {   // wave owns 5 atoms
    int p = pfx[a];
#pragma unroll
    for (int ch = 0; ch < EPM / 64; ++ch) {
      int e = ch * 64 + lane;
      bool match = ((int)ecol[e] == a);
      unsigned long long bal = __ballot(match);
      if (match) ssort[p + __popcll(bal & ((1ull << lane) - 1ull))] = epk[e];
      p += __popcll(bal);
    }
  }
  __syncthreads();
  for (int i = t; i < EPM; i += 512) ginfo[(size_t)g * EPM + i] = ssort[i];
  if (t < NPG) gstart[g * NPG + t] = pfx[t];
}

// ---------------- whole model per molecule: embed + 3 layers + head ----------------
__global__ void __launch_bounds__(512, 4) k_mol(
    const float* __restrict__ emb, const int* __restrict__ z,
    const unsigned* __restrict__ ginfo, const int* __restrict__ gstart,
    const ushort_t* __restrict__ tblb, const ushort_t* __restrict__ wtb,
    const float* __restrict__ cf_b2, const float* __restrict__ lin_b,
    const float* __restrict__ hw1, const float* __restrict__ hb1,
    const float* __restrict__ hw2, const float* __restrict__ hb2,
    float* __restrict__ out) {
  __shared__ ushort_t stab[TROWS * 128];  // 25,088 B (restaged per layer)
  __shared__ float sh[NPG][HID];          // 20,480 B fp32 residual h
  __shared__ ushort_t sb0[48 * 128];      // 12,288 B
  __shared__ ushort_t sb1[48 * 128];      // 12,288 B
  __shared__ unsigned smeta[EPM];         //  2,560 B
  __shared__ int sstart[NPG + 1];
  __shared__ float shead[NPG];
  int g = blockIdx.x, a0 = g * NPG, t = threadIdx.x;

  // ---- phase 0: stage everything ----
  {
    unsigned* b0u = (unsigned*)sb0;
    unsigned* b1u = (unsigned*)sb1;
    for (int i = t; i < NPG * 64; i += 512) {
      int row = i >> 6, cp = (i & 63) * 2;
      float2 v = *(const float2*)(emb + (size_t)z[a0 + row] * HID + cp);
      sh[row][cp] = v.x;
      sh[row][cp + 1] = v.y;
      b0u[bidx(row, cp) >> 1] = pk2(v.x, v.y);
    }
    for (int i = t; i < 8 * 64; i += 512) {
      int row = 40 + (i >> 6), cw = i & 63;
      b0u[row * 64 + cw] = 0u;
      b1u[row * 64 + cw] = 0u;
    }
    const unsigned* gin = ginfo + (size_t)g * EPM;
    for (int i = t; i < EPM; i += 512) smeta[i] = gin[i];
    if (t < NPG) sstart[t] = gstart[g * NPG + t];
    if (t == 0) sstart[NPG] = EPM;
    const uint4* ti4 = (const uint4*)tblb;
    uint4* st4 = (uint4*)stab;
    for (int i = t; i < TROWS * 128 / 8; i += 512) st4[i] = ti4[i];
  }
  __syncthreads();

  int w = t >> 6, l6 = t & 63;
  int r15 = l6 & 15, q = l6 >> 4;
  int colo = w * 16 + r15;

  for (int l = 0; l < 3; ++l) {
    const ushort_t* w1t = wtb + (size_t)(l * 3 + 0) * 128 * 128;
    const ushort_t* w2t = wtb + (size_t)(l * 3 + 1) * 128 * 128;
    const ushort_t* lwt = wtb + (size_t)(l * 3 + 2) * 128 * 128;
    const float* b2 = cf_b2 + (size_t)l * HID;
    const float* lb = lin_b + (size_t)l * HID;
    if (l > 0) {  // restage table (stab free after previous agg; sync at loop end)
      const uint4* ti4 = (const uint4*)(tblb + (size_t)l * TROWS * 128);
      uint4* st4 = (uint4*)stab;
      for (int i = t; i < TROWS * 128 / 8; i += 512) st4[i] = ti4[i];
    }
    // ---- GEMV1: x1 = h @ w1  (sb0 -> sb1) ----
    {
      short8v bfr[4];
      const ushort_t* wp = w1t + (size_t)colo * 128 + q * 8;
#pragma unroll
      for (int ks = 0; ks < 4; ++ks) bfr[ks] = *(const short8v*)(wp + ks * 32);
#pragma unroll
      for (int mt = 0; mt < 3; ++mt) {
        f32x4 acc = (f32x4){0.f, 0.f, 0.f, 0.f};
#pragma unroll
        for (int ks = 0; ks < 4; ++ks) {
          short8v af = *(const short8v*)&sb0[bidx(mt * 16 + r15, ks * 32 + q * 8)];
          acc = __builtin_amdgcn_mfma_f32_16x16x32_bf16(af, bfr[ks], acc, 0, 0, 0);
        }
#pragma unroll
        for (int r = 0; r < 4; ++r) sb1[bidx(mt * 16 + q * 4 + r, colo)] = bf16rne(acc[r]);
      }
    }
    __syncthreads();
    // ---- edge agg: owned-reduction, LDS table, (sb1 -> sb0) ----
    {
      const unsigned* tab32 = (const unsigned*)stab;
      const unsigned* b1u = (const unsigned*)sb1;
      unsigned* b0u = (unsigned*)sb0;
      for (int a = w; a < NPG; a += 8) {
        int kb = sstart[a], ke = sstart[a + 1];
        float accx = 0.f, accy = 0.f;
        for (int k = kb; k < ke; ++k) {
          unsigned m0 = smeta[k];
          int r0 = m0 >> 26;
          int i00 = (m0 >> 18) & 255;
          float t0 = (float)(m0 & 262143u) * (1.0f / 262144.0f);
          int base = i00 * 64 + l6;
          unsigned u0 = tab32[base];
          unsigned u1 = tab32[base + 64];
          unsigned u2 = tab32[base + 128];
          unsigned u3 = tab32[base + 192];
          unsigned xv = b1u[bidx(r0, 2 * l6) >> 1];
          float q2 = t0 * t0, q3 = q2 * t0;
          float w0 = 0.5f * (-q3 + 2.f * q2 - t0);
          float w1 = 0.5f * (3.f * q3 - 5.f * q2 + 2.f);
          float w2 = 0.5f * (-3.f * q3 + 4.f * q2 + t0);
          float w3 = 0.5f * (q3 - q2);
          float fx = w0 * bflo(u0);
          fx = fmaf(w1, bflo(u1), fx);
          fx = fmaf(w2, bflo(u2), fx);
          fx = fmaf(w3, bflo(u3), fx);
          float fy = w0 * bfhi(u0);
          fy = fmaf(w1, bfhi(u1), fy);
          fy = fmaf(w2, bfhi(u2), fy);
          fy = fmaf(w3, bfhi(u3), fy);
          accx = fmaf(bflo(xv), fx, accx);
          accy = fmaf(bfhi(xv), fy, accy);
        }
        b0u[bidx(a, 2 * l6) >> 1] = pk2(accx, accy);
      }
    }
    __syncthreads();
    // ---- GEMV2: u = ssp(agg @ w2 + b2)  (sb0 -> sb1) ----
    {
      float bc = b2[colo];
      short8v bfr[4];
      const ushort_t* wp = w2t + (size_t)colo * 128 + q * 8;
#pragma unroll
      for (int ks = 0; ks < 4; ++ks) bfr[ks] = *(const short8v*)(wp + ks * 32);
#pragma unroll
      for (int mt = 0; mt < 3; ++mt) {
        f32x4 acc = (f32x4){0.f, 0.f, 0.f, 0.f};
#pragma unroll
        for (int ks = 0; ks < 4; ++ks) {
          short8v af = *(const short8v*)&sb0[bidx(mt * 16 + r15, ks * 32 + q * 8)];
          acc = __builtin_amdgcn_mfma_f32_16x16x32_bf16(af, bfr[ks], acc, 0, 0, 0);
        }
#pragma unroll
        for (int r = 0; r < 4; ++r) {
          int row = mt * 16 + q * 4 + r;
          float v = (row < 40) ? ssp_f(acc[r] + bc) : 0.f;
          sb1[bidx(row, colo)] = bf16rne(v);
        }
      }
    }
    __syncthreads();
    // ---- GEMV3: h += u @ lw + lb  (sb1 -> sh fp32 + sb0 bf16) ----
    {
      float bc = lb[colo];
      short8v bfr[4];
      const ushort_t* wp = lwt + (size_t)colo * 128 + q * 8;
#pragma unroll
      for (int ks = 0; ks < 4; ++ks) bfr[ks] = *(const short8v*)(wp + ks * 32);
#pragma unroll
      for (int mt = 0; mt < 3; ++mt) {
        f32x4 acc = (f32x4){0.f, 0.f, 0.f, 0.f};
#pragma unroll
        for (int ks = 0; ks < 4; ++ks) {
          short8v af = *(const short8v*)&sb1[bidx(mt * 16 + r15, ks * 32 + q * 8)];
          acc = __builtin_amdgcn_mfma_f32_16x16x32_bf16(af, bfr[ks], acc, 0, 0, 0);
        }
#pragma unroll
        for (int r = 0; r < 4; ++r) {
          int row = mt * 16 + q * 4 + r;
          if (row < 40) {
            float nh = sh[row][colo] + acc[r] + bc;
            sh[row][colo] = nh;
            sb0[bidx(row, colo)] = bf16rne(nh);
          }
        }
      }
    }
    __syncthreads();
  }

  // ---- head (fp32): y = ssp(h@hw1+hb1)@hw2 + hb2; out[g] = sum ----
  {
    int a = w * 5;
    for (int p5 = 0; p5 < 5; ++p5, ++a) {
      float acc = hb1[l6];
      for (int k = 0; k < HID; k += 4) {
        float4 hv = *(const float4*)&sh[a][k];
        acc = fmaf(hv.x, hw1[(k + 0) * 64 + l6], acc);
        acc = fmaf(hv.y, hw1[(k + 1) * 64 + l6], acc);
        acc = fmaf(hv.z, hw1[(k + 2) * 64 + l6], acc);
        acc = fmaf(hv.w, hw1[(k + 3) * 64 + l6], acc);
      }
      float v = ssp_f(acc) * hw2[l6];
      for (int off = 32; off; off >>= 1) v += __shfl_down(v, off);
      if (l6 == 0) shead[a] = v;
    }
  }
  __syncthreads();
  if (t == 0) {
    float s = 0.f;
    for (int a = 0; a < NPG; ++a) s += shead[a];
    out[g] = s + (float)NPG * hb2[0];
  }
}

extern "C" void kernel_launch(void* const* d_in, const int* in_sizes, int n_in,
                              void* d_out, int out_size, void* d_ws, size_t ws_size,
                              hipStream_t stream) {
  const float* pos    = (const float*)d_in[0];
  const float* emb    = (const float*)d_in[1];
  const float* mlp_w1 = (const float*)d_in[2];
  const float* mlp_b1 = (const float*)d_in[3];
  const float* mlp_w2 = (const float*)d_in[4];
  const float* mlp_b2 = (const float*)d_in[5];
  const float* cf_w1  = (const float*)d_in[6];
  const float* cf_w2  = (const float*)d_in[7];
  const float* cf_b2  = (const float*)d_in[8];
  const float* lin_w  = (const float*)d_in[9];
  const float* lin_b  = (const float*)d_in[10];
  const float* hw1    = (const float*)d_in[11];
  const float* hb1    = (const float*)d_in[12];
  const float* hw2    = (const float*)d_in[13];
  const float* hb2    = (const float*)d_in[14];
  const int*   z      = (const int*)d_in[15];
  const int*   ei     = (const int*)d_in[17];

  ushort_t* tblb   = (ushort_t*)d_ws;                        // 3*TROWS*128 bf16
  ushort_t* wtb    = tblb + 3 * TROWS * 128;                 // 9*128*128 bf16
  int*      gstart = (int*)(wtb + 9 * 128 * 128);            // G*NPG
  unsigned* ginfo  = (unsigned*)(gstart + G_GRAPHS * NPG);   // E
  size_t need = (3ull * TROWS * 128 + 9ull * 128 * 128) * 2 +
                (size_t)G_GRAPHS * NPG * 4 + (size_t)E_EDGES * 4;
  if (ws_size < need) return;

  k_table<<<dim3((TROWS + 7) / 8, 3), NF, 0, stream>>>(mlp_w1, mlp_b1, mlp_w2, mlp_b2, tblb);
  k_prep<<<36, 256, 0, stream>>>(cf_w1, cf_w2, lin_w, wtb);
  k_csr<<<G_GRAPHS, 512, 0, stream>>>(pos, ei, ginfo, gstart);
  k_mol<<<G_GRAPHS, 512, 0, stream>>>(emb, z, ginfo, gstart, tblb, wtb,
                                      cf_b2, lin_b, hw1, hb1, hw2, hb2, (float*)d_out);
}

// Round 10
// 135.104 us; speedup vs baseline: 2.8695x; 1.2312x over previous
//
#include <hip/hip_runtime.h>
#include <math.h>

#define N_ATOMS 20000
#define G_GRAPHS 500
#define NPG 40
#define DEG 16
#define E_EDGES (N_ATOMS * DEG)
#define EPM (NPG * DEG)
#define HID 128
#define NF 128
#define TBL2 80
#define TROWS (TBL2 + 2)   // 82
#define CUTOFF 10.0f
#define LOG2F_ 0.6931471805599453f

typedef __attribute__((ext_vector_type(8))) short short8v;
typedef __attribute__((ext_vector_type(4))) float f32x4;
typedef unsigned short ushort_t;

__device__ __forceinline__ float ssp_f(float x) {
  float ax = fabsf(x);
  return fmaxf(x, 0.0f) + log1pf(expf(-ax)) - LOG2F_;
}
__device__ __forceinline__ ushort_t bf16rne(float x) {
  unsigned u = __float_as_uint(x);
  unsigned r = 0x7FFFu + ((u >> 16) & 1u);
  return (ushort_t)((u + r) >> 16);
}
__device__ __forceinline__ unsigned pk2(float a, float b) {
  return (unsigned)bf16rne(a) | ((unsigned)bf16rne(b) << 16);
}
__device__ __forceinline__ float bflo(unsigned u) { return __uint_as_float(u << 16); }
__device__ __forceinline__ float bfhi(unsigned u) { return __uint_as_float(u & 0xFFFF0000u); }
__device__ __forceinline__ int bidx(int row, int col) {
  return row * 128 + (col ^ ((row & 7) << 3));
}

// ---- filter tables (3 layers) -> bf16 [TROWS][128]; 8 rows/block ----
__global__ void k_table(const float* __restrict__ w1_, const float* __restrict__ b1_,
                        const float* __restrict__ w2_, const float* __restrict__ b2_,
                        ushort_t* __restrict__ table_) {
  __shared__ float eaT[NF][8];
  __shared__ float hvT[NF][8];
  int l = blockIdx.y;
  const float* w1 = w1_ + (size_t)l * NF * NF;
  const float* b1 = b1_ + (size_t)l * NF;
  const float* w2 = w2_ + (size_t)l * NF * NF;
  const float* b2 = b2_ + (size_t)l * NF;
  ushort_t* table = table_ + (size_t)l * TROWS * NF;
  int j = threadIdx.x;
  int rbase = blockIdx.x * 8;
  const float hh = CUTOFF / (float)(TBL2 - 1);
  const float delta = CUTOFF / (float)(NF - 1);
  const float coeff = -0.5f / (delta * delta);
#pragma unroll
  for (int rr = 0; rr < 8; ++rr) {
    float d = ((float)(rbase + rr) - 1.0f) * hh;
    float tt = d - delta * (float)j;
    eaT[j][rr] = expf(coeff * tt * tt);
  }
  __syncthreads();
  float acc[8], wreg[16];
  float b1j = b1[j];
#pragma unroll
  for (int rr = 0; rr < 8; ++rr) acc[rr] = b1j;
  for (int kb = 0; kb < NF; kb += 16) {
#pragma unroll
    for (int i = 0; i < 16; ++i) wreg[i] = w1[(kb + i) * NF + j];
#pragma unroll
    for (int i = 0; i < 16; ++i) {
      float4 e0 = *(const float4*)&eaT[kb + i][0];
      float4 e1 = *(const float4*)&eaT[kb + i][4];
      float wv = wreg[i];
      acc[0] = fmaf(e0.x, wv, acc[0]); acc[1] = fmaf(e0.y, wv, acc[1]);
      acc[2] = fmaf(e0.z, wv, acc[2]); acc[3] = fmaf(e0.w, wv, acc[3]);
      acc[4] = fmaf(e1.x, wv, acc[4]); acc[5] = fmaf(e1.y, wv, acc[5]);
      acc[6] = fmaf(e1.z, wv, acc[6]); acc[7] = fmaf(e1.w, wv, acc[7]);
    }
  }
#pragma unroll
  for (int rr = 0; rr < 8; ++rr) hvT[j][rr] = ssp_f(acc[rr]);
  __syncthreads();
  float b2j = b2[j];
#pragma unroll
  for (int rr = 0; rr < 8; ++rr) acc[rr] = b2j;
  for (int kb = 0; kb < NF; kb += 16) {
#pragma unroll
    for (int i = 0; i < 16; ++i) wreg[i] = w2[(kb + i) * NF + j];
#pragma unroll
    for (int i = 0; i < 16; ++i) {
      float4 e0 = *(const float4*)&hvT[kb + i][0];
      float4 e1 = *(const float4*)&hvT[kb + i][4];
      float wv = wreg[i];
      acc[0] = fmaf(e0.x, wv, acc[0]); acc[1] = fmaf(e0.y, wv, acc[1]);
      acc[2] = fmaf(e0.z, wv, acc[2]); acc[3] = fmaf(e0.w, wv, acc[3]);
      acc[4] = fmaf(e1.x, wv, acc[4]); acc[5] = fmaf(e1.y, wv, acc[5]);
      acc[6] = fmaf(e1.z, wv, acc[6]); acc[7] = fmaf(e1.w, wv, acc[7]);
    }
  }
#pragma unroll
  for (int rr = 0; rr < 8; ++rr) {
    int s = rbase + rr;
    if (s < TROWS) {
      float d = ((float)s - 1.0f) * hh;
      float C = 0.5f * (cosf(d * (float)M_PI / CUTOFF) + 1.0f);
      table[(size_t)s * NF + j] = bf16rne(acc[rr] * C);
    }
  }
}

// ---- one-time: transpose + bf16 weights. blocks 0-35: nine 128x128 GEMV mats;
//      blocks 36-37: head hw1 [128][64] -> slot 9 [64][128] ----
__global__ void k_prep(const float* __restrict__ cf_w1, const float* __restrict__ cf_w2,
                       const float* __restrict__ lin_w, const float* __restrict__ hw1,
                       ushort_t* __restrict__ wtb) {
  __shared__ float tile[32][33];
  int b = blockIdx.x;
  int t = threadIdx.x;
  int tr = t >> 5, tc = t & 31;
  if (b < 36) {
    int m = b >> 2, tj = b & 3;
    int l = m / 3, ty = m % 3;
    const float* src = (ty == 0 ? cf_w1 : ty == 1 ? cf_w2 : lin_w) + (size_t)l * 128 * 128;
    ushort_t* dst = wtb + (size_t)m * 128 * 128;
    for (int ti = 0; ti < 4; ++ti) {
      __syncthreads();
#pragma unroll
      for (int i = 0; i < 4; ++i) {
        int r = tr + i * 8;
        tile[r][tc] = src[(ti * 32 + r) * 128 + tj * 32 + tc];
      }
      __syncthreads();
#pragma unroll
      for (int i = 0; i < 4; ++i) {
        int r = tr + i * 8;
        dst[(tj * 32 + r) * 128 + ti * 32 + tc] = bf16rne(tile[tc][r]);
      }
    }
  } else {
    int tj = b - 36;  // 0..1 (j-stripes of 32, j<64)
    ushort_t* dst = wtb + (size_t)9 * 128 * 128;
    for (int ti = 0; ti < 4; ++ti) {
      __syncthreads();
#pragma unroll
      for (int i = 0; i < 4; ++i) {
        int r = tr + i * 8;
        tile[r][tc] = hw1[(ti * 32 + r) * 64 + tj * 32 + tc];
      }
      __syncthreads();
#pragma unroll
      for (int i = 0; i < 4; ++i) {
        int r = tr + i * 8;
        dst[(tj * 32 + r) * 128 + ti * 32 + tc] = bf16rne(tile[tc][r]);
      }
    }
  }
}

// ---- one-time: distances + cubic weights + CSR-by-destination ----
__global__ void __launch_bounds__(512) k_csr(const float* __restrict__ pos,
                                             const int* __restrict__ ei,
                                             ushort_t* __restrict__ gmeta,
                                             uint2* __restrict__ gw,
                                             int* __restrict__ gstart) {
  __shared__ float spos[NPG * 3];
  __shared__ int cnt[NPG];
  __shared__ int pfx[NPG + 1];
  __shared__ ushort_t emeta[EPM];
  __shared__ uint2 ew[EPM];
  __shared__ unsigned char ecol[EPM];
  __shared__ short ssidx[EPM];
  int g = blockIdx.x, a0 = g * NPG, t = threadIdx.x;
  if (t < NPG * 3) spos[t] = pos[a0 * 3 + t];
  if (t < NPG) cnt[t] = 0;
  __syncthreads();
  int ebase = a0 * DEG;
  const float tscale = (float)(TBL2 - 1) / CUTOFF;
  for (int i = t; i < EPM; i += 512) {
    int r = ei[ebase + i] - a0;
    int c = ei[E_EDGES + ebase + i] - a0;
    float dx = spos[3 * r + 0] - spos[3 * c + 0];
    float dy = spos[3 * r + 1] - spos[3 * c + 1];
    float dz = spos[3 * r + 2] - spos[3 * c + 2];
    float ft = sqrtf(dx * dx + dy * dy + dz * dz) * tscale;
    int i0 = min((int)ft, TBL2 - 2);
    float tt = ft - (float)i0;
    float t2 = tt * tt, t3 = t2 * tt;
    float w0 = 0.5f * (-t3 + 2.f * t2 - tt);
    float w1 = 0.5f * (3.f * t3 - 5.f * t2 + 2.f);
    float w2 = 0.5f * (-3.f * t3 + 4.f * t2 + tt);
    float w3 = 0.5f * (t3 - t2);
    emeta[i] = (ushort_t)((r << 8) | i0);
    ew[i] = make_uint2(pk2(w0, w1), pk2(w2, w3));
    ecol[i] = (unsigned char)c;
    atomicAdd(&cnt[c], 1);
  }
  __syncthreads();
  if (t == 0) {
    int s = 0;
    for (int a = 0; a < NPG; ++a) { pfx[a] = s; s += cnt[a]; }
    pfx[NPG] = s;
  }
  __syncthreads();
  int w = t >> 6, lane = t & 63;
  for (int a = w * 5; a < w * 5 + 5; ++a) {
    int p = pfx[a];
#pragma unroll
    for (int ch = 0; ch < EPM / 64; ++ch) {
      int e = ch * 64 + lane;
      bool match = ((int)ecol[e] == a);
      unsigned long long bal = __ballot(match);
      if (match) ssidx[p + __popcll(bal & ((1ull << lane) - 1ull))] = (short)e;
      p += __popcll(bal);
    }
  }
  __syncthreads();
  for (int i = t; i < EPM; i += 512) {
    int e = ssidx[i];
    gmeta[(size_t)g * EPM + i] = emeta[e];
    gw[(size_t)g * EPM + i] = ew[e];
  }
  if (t < NPG) gstart[g * NPG + t] = pfx[t];
}

// ---------------- whole model per molecule ----------------
__global__ void __launch_bounds__(512) k_mol(
    const float* __restrict__ emb, const int* __restrict__ z,
    const ushort_t* __restrict__ gmeta, const uint2* __restrict__ gw,
    const int* __restrict__ gstart, const ushort_t* __restrict__ tblb,
    const ushort_t* __restrict__ wtb, const float* __restrict__ cf_b2,
    const float* __restrict__ lin_b, const float* __restrict__ hb1,
    const float* __restrict__ hw2, const float* __restrict__ hb2,
    float* __restrict__ out) {
  __shared__ ushort_t stab[TROWS * 128];  // 20,992 B
  __shared__ ushort_t sb0[48 * 128];      // 12,288 B
  __shared__ ushort_t sb1[48 * 128];      // 12,288 B
  __shared__ ushort_t smeta[EPM];         //  1,280 B
  __shared__ uint2 swc[EPM];              //  5,120 B
  __shared__ int sstart[NPG + 1];
  __shared__ float shead[48];
  __shared__ int sz[NPG];
  int g = blockIdx.x, a0 = g * NPG, t = threadIdx.x;
  int w = t >> 6, l6 = t & 63, r15 = l6 & 15, q = l6 >> 4;
  int colo = w * 16 + r15;

  // ---- stage ----
  {
    if (t < NPG) sz[t] = z[a0 + t];
    const uint4* ti4 = (const uint4*)tblb;
    uint4* st4 = (uint4*)stab;
    for (int i = t; i < TROWS * 128 / 8; i += 512) st4[i] = ti4[i];
    const uint4* gm4 = (const uint4*)(gmeta + (size_t)g * EPM);
    uint4* sm4 = (uint4*)smeta;
    if (t < EPM * 2 / 16) sm4[t] = gm4[t];
    const uint4* gw4 = (const uint4*)(gw + (size_t)g * EPM);
    uint4* sw4 = (uint4*)swc;
    if (t < EPM * 8 / 16) sw4[t] = gw4[t];
    if (t < NPG) sstart[t] = gstart[g * NPG + t];
    if (t == 0) sstart[NPG] = EPM;
    if (t < 48) shead[t] = 0.f;
    ((unsigned*)sb0)[40 * 64 + t] = 0u;   // zero pad rows 40..47
    ((unsigned*)sb1)[40 * 64 + t] = 0u;
  }
  __syncthreads();

  // ---- h init from embedding: fragment registers + sb0 bf16 ----
  float hreg[12];
#pragma unroll
  for (int mt = 0; mt < 3; ++mt) {
#pragma unroll
    for (int r = 0; r < 4; ++r) {
      int row = mt * 16 + q * 4 + r;
      float v = 0.f;
      if (row < NPG) {
        v = emb[(size_t)sz[row] * HID + colo];
        sb0[bidx(row, colo)] = bf16rne(v);
      }
      hreg[mt * 4 + r] = v;
    }
  }
  __syncthreads();

  for (int l = 0; l < 3; ++l) {
    const ushort_t* w1t = wtb + (size_t)(l * 3 + 0) * 128 * 128;
    const ushort_t* w2t = wtb + (size_t)(l * 3 + 1) * 128 * 128;
    const ushort_t* lwt = wtb + (size_t)(l * 3 + 2) * 128 * 128;
    if (l > 0) {
      const uint4* ti4 = (const uint4*)(tblb + (size_t)l * TROWS * 128);
      uint4* st4 = (uint4*)stab;
      for (int i = t; i < TROWS * 128 / 8; i += 512) st4[i] = ti4[i];
    }
    // ---- GEMV1: x1 = h @ w1  (sb0 -> sb1) ----
    {
      short8v bfr[4];
      const ushort_t* wp = w1t + (size_t)colo * 128 + q * 8;
#pragma unroll
      for (int ks = 0; ks < 4; ++ks) bfr[ks] = *(const short8v*)(wp + ks * 32);
#pragma unroll
      for (int mt = 0; mt < 3; ++mt) {
        f32x4 acc = (f32x4){0.f, 0.f, 0.f, 0.f};
#pragma unroll
        for (int ks = 0; ks < 4; ++ks) {
          short8v af = *(const short8v*)&sb0[bidx(mt * 16 + r15, ks * 32 + q * 8)];
          acc = __builtin_amdgcn_mfma_f32_16x16x32_bf16(af, bfr[ks], acc, 0, 0, 0);
        }
#pragma unroll
        for (int r = 0; r < 4; ++r) sb1[bidx(mt * 16 + q * 4 + r, colo)] = bf16rne(acc[r]);
      }
    }
    __syncthreads();
    // ---- edge agg (precomputed cubic weights): sb1 -> sb0 ----
    {
      const unsigned* tabp = (const unsigned*)stab + l6;
      const unsigned* b1u = (const unsigned*)sb1;
      unsigned* b0u = (unsigned*)sb0;
      for (int a = w; a < NPG; a += 8) {
        int kb = sstart[a], ke = sstart[a + 1];
        float ax = 0.f, ay = 0.f;
        for (int k = kb; k < ke; ++k) {
          int mv = smeta[k];
          int r0 = mv >> 8, i00 = mv & 255;
          uint2 wc = swc[k];
          const unsigned* tb = tabp + (i00 << 6);
          unsigned u0 = tb[0], u1 = tb[64], u2 = tb[128], u3 = tb[192];
          unsigned xv = b1u[(r0 << 6) + (l6 ^ ((r0 & 7) << 2))];
          float w0 = bflo(wc.x), w1 = bfhi(wc.x);
          float w2 = bflo(wc.y), w3 = bfhi(wc.y);
          float fx = w0 * bflo(u0);
          fx = fmaf(w1, bflo(u1), fx);
          fx = fmaf(w2, bflo(u2), fx);
          fx = fmaf(w3, bflo(u3), fx);
          float fy = w0 * bfhi(u0);
          fy = fmaf(w1, bfhi(u1), fy);
          fy = fmaf(w2, bfhi(u2), fy);
          fy = fmaf(w3, bfhi(u3), fy);
          ax = fmaf(bflo(xv), fx, ax);
          ay = fmaf(bfhi(xv), fy, ay);
        }
        b0u[(a << 6) + (l6 ^ ((a & 7) << 2))] = pk2(ax, ay);
      }
    }
    __syncthreads();
    // ---- GEMV2: u = ssp(agg @ w2 + b2)  (sb0 -> sb1) ----
    {
      float bc = cf_b2[(size_t)l * HID + colo];
      short8v bfr[4];
      const ushort_t* wp = w2t + (size_t)colo * 128 + q * 8;
#pragma unroll
      for (int ks = 0; ks < 4; ++ks) bfr[ks] = *(const short8v*)(wp + ks * 32);
#pragma unroll
      for (int mt = 0; mt < 3; ++mt) {
        f32x4 acc = (f32x4){0.f, 0.f, 0.f, 0.f};
#pragma unroll
        for (int ks = 0; ks < 4; ++ks) {
          short8v af = *(const short8v*)&sb0[bidx(mt * 16 + r15, ks * 32 + q * 8)];
          acc = __builtin_amdgcn_mfma_f32_16x16x32_bf16(af, bfr[ks], acc, 0, 0, 0);
        }
#pragma unroll
        for (int r = 0; r < 4; ++r) {
          int row = mt * 16 + q * 4 + r;
          float v = (row < NPG) ? ssp_f(acc[r] + bc) : 0.f;
          sb1[bidx(row, colo)] = bf16rne(v);
        }
      }
    }
    __syncthreads();
    // ---- GEMV3: h += u @ lw + lb  (sb1 -> hreg + sb0 bf16) ----
    {
      float bc = lin_b[(size_t)l * HID + colo];
      short8v bfr[4];
      const ushort_t* wp = lwt + (size_t)colo * 128 + q * 8;
#pragma unroll
      for (int ks = 0; ks < 4; ++ks) bfr[ks] = *(const short8v*)(wp + ks * 32);
#pragma unroll
      for (int mt = 0; mt < 3; ++mt) {
        f32x4 acc = (f32x4){0.f, 0.f, 0.f, 0.f};
#pragma unroll
        for (int ks = 0; ks < 4; ++ks) {
          short8v af = *(const short8v*)&sb1[bidx(mt * 16 + r15, ks * 32 + q * 8)];
          acc = __builtin_amdgcn_mfma_f32_16x16x32_bf16(af, bfr[ks], acc, 0, 0, 0);
        }
#pragma unroll
        for (int r = 0; r < 4; ++r) {
          int row = mt * 16 + q * 4 + r;
          if (row < NPG) {
            float nh = hreg[mt * 4 + r] + acc[r] + bc;
            hreg[mt * 4 + r] = nh;
            sb0[bidx(row, colo)] = bf16rne(nh);
          }
        }
      }
    }
    __syncthreads();
  }

  // ---- head via MFMA: y = ssp(H@hw1+hb1)@hw2; out[g] = sum + 40*hb2 ----
  {
    const ushort_t* h1t = wtb + (size_t)9 * 128 * 128;
    for (int tile = w; tile < 12; tile += 8) {
      int mt = tile >> 2, nt = tile & 3;
      int col = nt * 16 + r15;
      short8v bfr[4];
      const ushort_t* wp = h1t + (size_t)col * 128 + q * 8;
#pragma unroll
      for (int ks = 0; ks < 4; ++ks) bfr[ks] = *(const short8v*)(wp + ks * 32);
      f32x4 acc = (f32x4){0.f, 0.f, 0.f, 0.f};
#pragma unroll
      for (int ks = 0; ks < 4; ++ks) {
        short8v af = *(const short8v*)&sb0[bidx(mt * 16 + r15, ks * 32 + q * 8)];
        acc = __builtin_amdgcn_mfma_f32_16x16x32_bf16(af, bfr[ks], acc, 0, 0, 0);
      }
      float hb = hb1[col];
      float w2v = hw2[col];
#pragma unroll
      for (int r = 0; r < 4; ++r) {
        int row = mt * 16 + q * 4 + r;
        float y = ssp_f(acc[r] + hb) * w2v;
        y += __shfl_xor(y, 1);
        y += __shfl_xor(y, 2);
        y += __shfl_xor(y, 4);
        y += __shfl_xor(y, 8);
        if (r15 == 0 && row < NPG) atomicAdd(&shead[row], y);
      }
    }
  }
  __syncthreads();
  if (w == 0) {
    float v = (l6 < NPG) ? shead[l6] : 0.f;
#pragma unroll
    for (int off = 32; off; off >>= 1) v += __shfl_xor(v, off);
    if (l6 == 0) out[g] = v + (float)NPG * hb2[0];
  }
}

extern "C" void kernel_launch(void* const* d_in, const int* in_sizes, int n_in,
                              void* d_out, int out_size, void* d_ws, size_t ws_size,
                              hipStream_t stream) {
  const float* pos    = (const float*)d_in[0];
  const float* emb    = (const float*)d_in[1];
  const float* mlp_w1 = (const float*)d_in[2];
  const float* mlp_b1 = (const float*)d_in[3];
  const float* mlp_w2 = (const float*)d_in[4];
  const float* mlp_b2 = (const float*)d_in[5];
  const float* cf_w1  = (const float*)d_in[6];
  const float* cf_w2  = (const float*)d_in[7];
  const float* cf_b2  = (const float*)d_in[8];
  const float* lin_w  = (const float*)d_in[9];
  const float* lin_b  = (const float*)d_in[10];
  const float* hw1    = (const float*)d_in[11];
  const float* hb1    = (const float*)d_in[12];
  const float* hw2    = (const float*)d_in[13];
  const float* hb2    = (const float*)d_in[14];
  const int*   z      = (const int*)d_in[15];
  const int*   ei     = (const int*)d_in[17];

  char* wsb = (char*)d_ws;
  uint2*    gw     = (uint2*)wsb;                               // E*8 = 2,560,000
  int*      gstart = (int*)(wsb + 2560000);                     // 80,000
  ushort_t* gmeta  = (ushort_t*)(wsb + 2640000);                // 640,000
  ushort_t* tblb   = (ushort_t*)(wsb + 3280000);                // 3*82*128*2 = 62,976
  ushort_t* wtb    = (ushort_t*)(wsb + 3342976);                // 10*16384*2 = 327,680
  size_t need = 3342976 + 327680;
  if (ws_size < need) return;

  k_table<<<dim3((TROWS + 7) / 8, 3), NF, 0, stream>>>(mlp_w1, mlp_b1, mlp_w2, mlp_b2, tblb);
  k_prep<<<38, 256, 0, stream>>>(cf_w1, cf_w2, lin_w, hw1, wtb);
  k_csr<<<G_GRAPHS, 512, 0, stream>>>(pos, ei, gmeta, gw, gstart);
  k_mol<<<G_GRAPHS, 512, 0, stream>>>(emb, z, gmeta, gw, gstart, tblb, wtb,
                                      cf_b2, lin_b, hb1, hw2, hb2, (float*)d_out);
}

// Round 11
// 117.095 us; speedup vs baseline: 3.3108x; 1.1538x over previous
//
#include <hip/hip_runtime.h>
#include <math.h>

#define N_ATOMS 20000
#define G_GRAPHS 500
#define NPG 40
#define DEG 16
#define E_EDGES (N_ATOMS * DEG)
#define EPM (NPG * DEG)
#define HID 128
#define NF 128
#define TBL2 80
#define TROWS (TBL2 + 2)   // 82 stored rows (grid -1 .. 80)
#define PROWS 81           // pair rows s=0..80: (row s, row s+1)
#define CUTOFF 10.0f
#define LOG2F_ 0.6931471805599453f

typedef __attribute__((ext_vector_type(8))) short short8v;
typedef __attribute__((ext_vector_type(4))) float f32x4;
typedef __attribute__((ext_vector_type(2))) __bf16 bf16x2;
typedef unsigned short ushort_t;

__device__ __forceinline__ float ssp_f(float x) {
  float ax = fabsf(x);
  return fmaxf(x, 0.0f) + log1pf(expf(-ax)) - LOG2F_;
}
__device__ __forceinline__ ushort_t bf16rne(float x) {
  unsigned u = __float_as_uint(x);
  unsigned r = 0x7FFFu + ((u >> 16) & 1u);
  return (ushort_t)((u + r) >> 16);
}
__device__ __forceinline__ unsigned pk2(float a, float b) {
  return (unsigned)bf16rne(a) | ((unsigned)bf16rne(b) << 16);
}
__device__ __forceinline__ float bflo(unsigned u) { return __uint_as_float(u << 16); }
__device__ __forceinline__ float bfhi(unsigned u) { return __uint_as_float(u & 0xFFFF0000u); }
__device__ __forceinline__ int bidx(int row, int col) {
  return row * 128 + (col ^ ((row & 7) << 3));
}
// dot2 of two packed-bf16 pairs + accumulate (HW dot2 if available; exact fma fallback)
__device__ __forceinline__ float fdot2b(unsigned a, unsigned b, float c) {
#if defined(__has_builtin) && __has_builtin(__builtin_amdgcn_fdot2_f32_bf16)
  return __builtin_amdgcn_fdot2_f32_bf16(__builtin_bit_cast(bf16x2, a),
                                         __builtin_bit_cast(bf16x2, b), c, false);
#else
  return fmaf(bflo(a), bflo(b), fmaf(bfhi(a), bfhi(b), c));
#endif
}

// ---- filter tables (3 layers) -> bf16 [TROWS][128]; 8 rows/block ----
__global__ void k_table(const float* __restrict__ w1_, const float* __restrict__ b1_,
                        const float* __restrict__ w2_, const float* __restrict__ b2_,
                        ushort_t* __restrict__ table_) {
  __shared__ float eaT[NF][8];
  __shared__ float hvT[NF][8];
  int l = blockIdx.y;
  const float* w1 = w1_ + (size_t)l * NF * NF;
  const float* b1 = b1_ + (size_t)l * NF;
  const float* w2 = w2_ + (size_t)l * NF * NF;
  const float* b2 = b2_ + (size_t)l * NF;
  ushort_t* table = table_ + (size_t)l * TROWS * NF;
  int j = threadIdx.x;
  int rbase = blockIdx.x * 8;
  const float hh = CUTOFF / (float)(TBL2 - 1);
  const float delta = CUTOFF / (float)(NF - 1);
  const float coeff = -0.5f / (delta * delta);
#pragma unroll
  for (int rr = 0; rr < 8; ++rr) {
    float d = ((float)(rbase + rr) - 1.0f) * hh;
    float tt = d - delta * (float)j;
    eaT[j][rr] = expf(coeff * tt * tt);
  }
  __syncthreads();
  float acc[8], wreg[16];
  float b1j = b1[j];
#pragma unroll
  for (int rr = 0; rr < 8; ++rr) acc[rr] = b1j;
  for (int kb = 0; kb < NF; kb += 16) {
#pragma unroll
    for (int i = 0; i < 16; ++i) wreg[i] = w1[(kb + i) * NF + j];
#pragma unroll
    for (int i = 0; i < 16; ++i) {
      float4 e0 = *(const float4*)&eaT[kb + i][0];
      float4 e1 = *(const float4*)&eaT[kb + i][4];
      float wv = wreg[i];
      acc[0] = fmaf(e0.x, wv, acc[0]); acc[1] = fmaf(e0.y, wv, acc[1]);
      acc[2] = fmaf(e0.z, wv, acc[2]); acc[3] = fmaf(e0.w, wv, acc[3]);
      acc[4] = fmaf(e1.x, wv, acc[4]); acc[5] = fmaf(e1.y, wv, acc[5]);
      acc[6] = fmaf(e1.z, wv, acc[6]); acc[7] = fmaf(e1.w, wv, acc[7]);
    }
  }
#pragma unroll
  for (int rr = 0; rr < 8; ++rr) hvT[j][rr] = ssp_f(acc[rr]);
  __syncthreads();
  float b2j = b2[j];
#pragma unroll
  for (int rr = 0; rr < 8; ++rr) acc[rr] = b2j;
  for (int kb = 0; kb < NF; kb += 16) {
#pragma unroll
    for (int i = 0; i < 16; ++i) wreg[i] = w2[(kb + i) * NF + j];
#pragma unroll
    for (int i = 0; i < 16; ++i) {
      float4 e0 = *(const float4*)&hvT[kb + i][0];
      float4 e1 = *(const float4*)&hvT[kb + i][4];
      float wv = wreg[i];
      acc[0] = fmaf(e0.x, wv, acc[0]); acc[1] = fmaf(e0.y, wv, acc[1]);
      acc[2] = fmaf(e0.z, wv, acc[2]); acc[3] = fmaf(e0.w, wv, acc[3]);
      acc[4] = fmaf(e1.x, wv, acc[4]); acc[5] = fmaf(e1.y, wv, acc[5]);
      acc[6] = fmaf(e1.z, wv, acc[6]); acc[7] = fmaf(e1.w, wv, acc[7]);
    }
  }
#pragma unroll
  for (int rr = 0; rr < 8; ++rr) {
    int s = rbase + rr;
    if (s < TROWS) {
      float d = ((float)s - 1.0f) * hh;
      float C = 0.5f * (cosf(d * (float)M_PI / CUTOFF) + 1.0f);
      table[(size_t)s * NF + j] = bf16rne(acc[rr] * C);
    }
  }
}

// ---- one-time: transpose + bf16 weights (9 GEMV mats + head hw1 -> slot 9) ----
__global__ void k_prep(const float* __restrict__ cf_w1, const float* __restrict__ cf_w2,
                       const float* __restrict__ lin_w, const float* __restrict__ hw1,
                       ushort_t* __restrict__ wtb) {
  __shared__ float tile[32][33];
  int b = blockIdx.x;
  int t = threadIdx.x;
  int tr = t >> 5, tc = t & 31;
  if (b < 36) {
    int m = b >> 2, tj = b & 3;
    int l = m / 3, ty = m % 3;
    const float* src = (ty == 0 ? cf_w1 : ty == 1 ? cf_w2 : lin_w) + (size_t)l * 128 * 128;
    ushort_t* dst = wtb + (size_t)m * 128 * 128;
    for (int ti = 0; ti < 4; ++ti) {
      __syncthreads();
#pragma unroll
      for (int i = 0; i < 4; ++i) {
        int r = tr + i * 8;
        tile[r][tc] = src[(ti * 32 + r) * 128 + tj * 32 + tc];
      }
      __syncthreads();
#pragma unroll
      for (int i = 0; i < 4; ++i) {
        int r = tr + i * 8;
        dst[(tj * 32 + r) * 128 + ti * 32 + tc] = bf16rne(tile[tc][r]);
      }
    }
  } else {
    int tj = b - 36;
    ushort_t* dst = wtb + (size_t)9 * 128 * 128;
    for (int ti = 0; ti < 4; ++ti) {
      __syncthreads();
#pragma unroll
      for (int i = 0; i < 4; ++i) {
        int r = tr + i * 8;
        tile[r][tc] = hw1[(ti * 32 + r) * 64 + tj * 32 + tc];
      }
      __syncthreads();
#pragma unroll
      for (int i = 0; i < 4; ++i) {
        int r = tr + i * 8;
        dst[(tj * 32 + r) * 128 + ti * 32 + tc] = bf16rne(tile[tc][r]);
      }
    }
  }
}

// ---- one-time: distances + cubic weights + CSR-by-destination; one uint4/edge ----
// ev = { pk2(w0,w1), pk2(w2,w3), i0*128, (r<<6) | (((r&7)<<2)<<16) }
__global__ void __launch_bounds__(512) k_csr(const float* __restrict__ pos,
                                             const int* __restrict__ ei,
                                             uint4* __restrict__ ge,
                                             int* __restrict__ gstart) {
  __shared__ float spos[NPG * 3];
  __shared__ int cnt[NPG];
  __shared__ int pfx[NPG + 1];
  __shared__ uint4 epk[EPM];
  __shared__ unsigned char ecol[EPM];
  __shared__ short ssidx[EPM];
  int g = blockIdx.x, a0 = g * NPG, t = threadIdx.x;
  if (t < NPG * 3) spos[t] = pos[a0 * 3 + t];
  if (t < NPG) cnt[t] = 0;
  __syncthreads();
  int ebase = a0 * DEG;
  const float tscale = (float)(TBL2 - 1) / CUTOFF;
  for (int i = t; i < EPM; i += 512) {
    int r = ei[ebase + i] - a0;
    int c = ei[E_EDGES + ebase + i] - a0;
    float dx = spos[3 * r + 0] - spos[3 * c + 0];
    float dy = spos[3 * r + 1] - spos[3 * c + 1];
    float dz = spos[3 * r + 2] - spos[3 * c + 2];
    float ft = sqrtf(dx * dx + dy * dy + dz * dz) * tscale;
    int i0 = min((int)ft, TBL2 - 2);
    float tt = ft - (float)i0;
    float t2 = tt * tt, t3 = t2 * tt;
    float w0 = 0.5f * (-t3 + 2.f * t2 - tt);
    float w1 = 0.5f * (3.f * t3 - 5.f * t2 + 2.f);
    float w2 = 0.5f * (-3.f * t3 + 4.f * t2 + tt);
    float w3 = 0.5f * (t3 - t2);
    epk[i] = make_uint4(pk2(w0, w1), pk2(w2, w3), (unsigned)(i0 << 7),
                        (unsigned)((r << 6) | (((r & 7) << 2) << 16)));
    ecol[i] = (unsigned char)c;
    atomicAdd(&cnt[c], 1);
  }
  __syncthreads();
  if (t == 0) {
    int s = 0;
    for (int a = 0; a < NPG; ++a) { pfx[a] = s; s += cnt[a]; }
    pfx[NPG] = s;
  }
  __syncthreads();
  int w = t >> 6, lane = t & 63;
  for (int a = w * 5; a < w * 5 + 5; ++a) {
    int p = pfx[a];
#pragma unroll
    for (int ch = 0; ch < EPM / 64; ++ch) {
      int e = ch * 64 + lane;
      bool match = ((int)ecol[e] == a);
      unsigned long long bal = __ballot(match);
      if (match) ssidx[p + __popcll(bal & ((1ull << lane) - 1ull))] = (short)e;
      p += __popcll(bal);
    }
  }
  __syncthreads();
  for (int i = t; i < EPM; i += 512) ge[(size_t)g * EPM + i] = epk[ssidx[i]];
  if (t < NPG) gstart[g * NPG + t] = pfx[t];
}

// ---------------- whole model per molecule ----------------
__global__ void __launch_bounds__(512) k_mol(
    const float* __restrict__ emb, const int* __restrict__ z,
    const uint4* __restrict__ ge, const int* __restrict__ gstart,
    const ushort_t* __restrict__ tblb, const ushort_t* __restrict__ wtb,
    const float* __restrict__ cf_b2, const float* __restrict__ lin_b,
    const float* __restrict__ hb1, const float* __restrict__ hw2,
    const float* __restrict__ hb2, float* __restrict__ out) {
  __shared__ unsigned ptab[PROWS * 128];  // 41,472 B pair-packed table
  __shared__ ushort_t sb0[48 * 128];      // 12,288 B
  __shared__ ushort_t sb1[48 * 128];      // 12,288 B
  __shared__ uint4 sedge[EPM];            // 10,240 B
  __shared__ int sstart[NPG + 1];
  __shared__ float shead[48];
  __shared__ int sz[NPG];
  int g = blockIdx.x, a0 = g * NPG, t = threadIdx.x;
  int w = t >> 6, l6 = t & 63, r15 = l6 & 15, q = l6 >> 4;
  int colo = w * 16 + r15;

  // ---- stage ----
  {
    if (t < NPG) sz[t] = z[a0 + t];
    const uint4* gsrc = ge + (size_t)g * EPM;
    for (int i = t; i < EPM; i += 512) sedge[i] = gsrc[i];
    if (t < NPG) sstart[t] = gstart[g * NPG + t];
    if (t == 0) sstart[NPG] = EPM;
    if (t < 48) shead[t] = 0.f;
    ((unsigned*)sb0)[40 * 64 + t] = 0u;  // zero pad rows 40..47
    ((unsigned*)sb1)[40 * 64 + t] = 0u;
    // pair-pack layer-0 table
    const ushort_t* tg = tblb;
    for (int i = t; i < PROWS * 32; i += 512) {
      int s = i >> 5, c4 = (i & 31) << 2;
      uint2 ar = *(const uint2*)(tg + s * 128 + c4);
      uint2 br = *(const uint2*)(tg + (s + 1) * 128 + c4);
      uint4 o;
      o.x = (ar.x & 0xffffu) | (br.x << 16);
      o.y = (ar.x >> 16) | (br.x & 0xffff0000u);
      o.z = (ar.y & 0xffffu) | (br.y << 16);
      o.w = (ar.y >> 16) | (br.y & 0xffff0000u);
      *(uint4*)&ptab[(s << 7) + c4] = o;
    }
  }
  __syncthreads();

  // ---- h init from embedding: fragment registers + sb0 bf16 ----
  float hreg[12];
#pragma unroll
  for (int mt = 0; mt < 3; ++mt) {
#pragma unroll
    for (int r = 0; r < 4; ++r) {
      int row = mt * 16 + q * 4 + r;
      float v = 0.f;
      if (row < NPG) {
        v = emb[(size_t)sz[row] * HID + colo];
        sb0[bidx(row, colo)] = bf16rne(v);
      }
      hreg[mt * 4 + r] = v;
    }
  }
  __syncthreads();

  for (int l = 0; l < 3; ++l) {
    const ushort_t* w1t = wtb + (size_t)(l * 3 + 0) * 128 * 128;
    const ushort_t* w2t = wtb + (size_t)(l * 3 + 1) * 128 * 128;
    const ushort_t* lwt = wtb + (size_t)(l * 3 + 2) * 128 * 128;
    if (l > 0) {  // restage pair table (safe: ptab unread until after next barrier)
      const ushort_t* tg = tblb + (size_t)l * TROWS * 128;
      for (int i = t; i < PROWS * 32; i += 512) {
        int s = i >> 5, c4 = (i & 31) << 2;
        uint2 ar = *(const uint2*)(tg + s * 128 + c4);
        uint2 br = *(const uint2*)(tg + (s + 1) * 128 + c4);
        uint4 o;
        o.x = (ar.x & 0xffffu) | (br.x << 16);
        o.y = (ar.x >> 16) | (br.x & 0xffff0000u);
        o.z = (ar.y & 0xffffu) | (br.y << 16);
        o.w = (ar.y >> 16) | (br.y & 0xffff0000u);
        *(uint4*)&ptab[(s << 7) + c4] = o;
      }
    }
    // ---- GEMV1: x1 = h @ w1  (sb0 -> sb1) ----
    {
      short8v bfr[4];
      const ushort_t* wp = w1t + (size_t)colo * 128 + q * 8;
#pragma unroll
      for (int ks = 0; ks < 4; ++ks) bfr[ks] = *(const short8v*)(wp + ks * 32);
#pragma unroll
      for (int mt = 0; mt < 3; ++mt) {
        f32x4 acc = (f32x4){0.f, 0.f, 0.f, 0.f};
#pragma unroll
        for (int ks = 0; ks < 4; ++ks) {
          short8v af = *(const short8v*)&sb0[bidx(mt * 16 + r15, ks * 32 + q * 8)];
          acc = __builtin_amdgcn_mfma_f32_16x16x32_bf16(af, bfr[ks], acc, 0, 0, 0);
        }
#pragma unroll
        for (int r = 0; r < 4; ++r) sb1[bidx(mt * 16 + q * 4 + r, colo)] = bf16rne(acc[r]);
      }
    }
    __syncthreads();
    // ---- edge agg: pair-table + dot2, owned-reduction (sb1 -> sb0) ----
    {
      const unsigned* ptabL = ptab + (l6 << 1);
      const unsigned* b1u = (const unsigned*)sb1;
      unsigned* b0u = (unsigned*)sb0;
      const uint4* se = sedge;
      for (int a = w; a < NPG; a += 8) {
        int kb = sstart[a], ke = sstart[a + 1];
        float ax = 0.f, ay = 0.f;
        for (int k = kb; k < ke; ++k) {
          uint4 ev = se[k];
          const unsigned* tb = ptabL + ev.z;
          uint2 pa = *(const uint2*)tb;
          uint2 pb = *(const uint2*)(tb + 256);
          unsigned xv = b1u[(ev.w & 0xffffu) + (l6 ^ (ev.w >> 16))];
          float fx = fdot2b(ev.x, pa.x, 0.f);
          fx = fdot2b(ev.y, pb.x, fx);
          float fy = fdot2b(ev.x, pa.y, 0.f);
          fy = fdot2b(ev.y, pb.y, fy);
          ax = fmaf(bflo(xv), fx, ax);
          ay = fmaf(bfhi(xv), fy, ay);
        }
        b0u[(a << 6) + (l6 ^ ((a & 7) << 2))] = pk2(ax, ay);
      }
    }
    __syncthreads();
    // ---- GEMV2: u = ssp(agg @ w2 + b2)  (sb0 -> sb1) ----
    {
      float bc = cf_b2[(size_t)l * HID + colo];
      short8v bfr[4];
      const ushort_t* wp = w2t + (size_t)colo * 128 + q * 8;
#pragma unroll
      for (int ks = 0; ks < 4; ++ks) bfr[ks] = *(const short8v*)(wp + ks * 32);
#pragma unroll
      for (int mt = 0; mt < 3; ++mt) {
        f32x4 acc = (f32x4){0.f, 0.f, 0.f, 0.f};
#pragma unroll
        for (int ks = 0; ks < 4; ++ks) {
          short8v af = *(const short8v*)&sb0[bidx(mt * 16 + r15, ks * 32 + q * 8)];
          acc = __builtin_amdgcn_mfma_f32_16x16x32_bf16(af, bfr[ks], acc, 0, 0, 0);
        }
#pragma unroll
        for (int r = 0; r < 4; ++r) {
          int row = mt * 16 + q * 4 + r;
          float v = (row < NPG) ? ssp_f(acc[r] + bc) : 0.f;
          sb1[bidx(row, colo)] = bf16rne(v);
        }
      }
    }
    __syncthreads();
    // ---- GEMV3: h += u @ lw + lb  (sb1 -> hreg + sb0 bf16) ----
    {
      float bc = lin_b[(size_t)l * HID + colo];
      short8v bfr[4];
      const ushort_t* wp = lwt + (size_t)colo * 128 + q * 8;
#pragma unroll
      for (int ks = 0; ks < 4; ++ks) bfr[ks] = *(const short8v*)(wp + ks * 32);
#pragma unroll
      for (int mt = 0; mt < 3; ++mt) {
        f32x4 acc = (f32x4){0.f, 0.f, 0.f, 0.f};
#pragma unroll
        for (int ks = 0; ks < 4; ++ks) {
          short8v af = *(const short8v*)&sb1[bidx(mt * 16 + r15, ks * 32 + q * 8)];
          acc = __builtin_amdgcn_mfma_f32_16x16x32_bf16(af, bfr[ks], acc, 0, 0, 0);
        }
#pragma unroll
        for (int r = 0; r < 4; ++r) {
          int row = mt * 16 + q * 4 + r;
          if (row < NPG) {
            float nh = hreg[mt * 4 + r] + acc[r] + bc;
            hreg[mt * 4 + r] = nh;
            sb0[bidx(row, colo)] = bf16rne(nh);
          }
        }
      }
    }
    __syncthreads();
  }

  // ---- head via MFMA: y = ssp(H@hw1+hb1)@hw2; out[g] = sum + 40*hb2 ----
  {
    const ushort_t* h1t = wtb + (size_t)9 * 128 * 128;
    for (int tile = w; tile < 12; tile += 8) {
      int mt = tile >> 2, nt = tile & 3;
      int col = nt * 16 + r15;
      short8v bfr[4];
      const ushort_t* wp = h1t + (size_t)col * 128 + q * 8;
#pragma unroll
      for (int ks = 0; ks < 4; ++ks) bfr[ks] = *(const short8v*)(wp + ks * 32);
      f32x4 acc = (f32x4){0.f, 0.f, 0.f, 0.f};
#pragma unroll
      for (int ks = 0; ks < 4; ++ks) {
        short8v af = *(const short8v*)&sb0[bidx(mt * 16 + r15, ks * 32 + q * 8)];
        acc = __builtin_amdgcn_mfma_f32_16x16x32_bf16(af, bfr[ks], acc, 0, 0, 0);
      }
      float hb = hb1[col];
      float w2v = hw2[col];
#pragma unroll
      for (int r = 0; r < 4; ++r) {
        int row = mt * 16 + q * 4 + r;
        float y = ssp_f(acc[r] + hb) * w2v;
        y += __shfl_xor(y, 1);
        y += __shfl_xor(y, 2);
        y += __shfl_xor(y, 4);
        y += __shfl_xor(y, 8);
        if (r15 == 0 && row < NPG) atomicAdd(&shead[row], y);
      }
    }
  }
  __syncthreads();
  if (w == 0) {
    float v = (l6 < NPG) ? shead[l6] : 0.f;
#pragma unroll
    for (int off = 32; off; off >>= 1) v += __shfl_xor(v, off);
    if (l6 == 0) out[g] = v + (float)NPG * hb2[0];
  }
}

extern "C" void kernel_launch(void* const* d_in, const int* in_sizes, int n_in,
                              void* d_out, int out_size, void* d_ws, size_t ws_size,
                              hipStream_t stream) {
  const float* pos    = (const float*)d_in[0];
  const float* emb    = (const float*)d_in[1];
  const float* mlp_w1 = (const float*)d_in[2];
  const float* mlp_b1 = (const float*)d_in[3];
  const float* mlp_w2 = (const float*)d_in[4];
  const float* mlp_b2 = (const float*)d_in[5];
  const float* cf_w1  = (const float*)d_in[6];
  const float* cf_w2  = (const float*)d_in[7];
  const float* cf_b2  = (const float*)d_in[8];
  const float* lin_w  = (const float*)d_in[9];
  const float* lin_b  = (const float*)d_in[10];
  const float* hw1    = (const float*)d_in[11];
  const float* hb1    = (const float*)d_in[12];
  const float* hw2    = (const float*)d_in[13];
  const float* hb2    = (const float*)d_in[14];
  const int*   z      = (const int*)d_in[15];
  const int*   ei     = (const int*)d_in[17];

  char* wsb = (char*)d_ws;
  uint4*    ge     = (uint4*)wsb;                       // E*16 = 5,120,000
  int*      gstart = (int*)(wsb + 5120000);             // 80,000
  ushort_t* tblb   = (ushort_t*)(wsb + 5200000);        // 3*82*128*2 = 62,976
  ushort_t* wtb    = (ushort_t*)(wsb + 5262976);        // 10*16384*2 = 327,680
  size_t need = 5262976 + 327680;
  if (ws_size < need) return;

  k_table<<<dim3((TROWS + 7) / 8, 3), NF, 0, stream>>>(mlp_w1, mlp_b1, mlp_w2, mlp_b2, tblb);
  k_prep<<<38, 256, 0, stream>>>(cf_w1, cf_w2, lin_w, hw1, wtb);
  k_csr<<<G_GRAPHS, 512, 0, stream>>>(pos, ei, ge, gstart);
  k_mol<<<G_GRAPHS, 512, 0, stream>>>(emb, z, ge, gstart, tblb, wtb,
                                      cf_b2, lin_b, hb1, hw2, hb2, (float*)d_out);
}

// Round 12
// 113.418 us; speedup vs baseline: 3.4181x; 1.0324x over previous
//
#include <hip/hip_runtime.h>
#include <math.h>

#define N_ATOMS 20000
#define G_GRAPHS 500
#define NPG 40
#define DEG 16
#define E_EDGES (N_ATOMS * DEG)
#define EPM (NPG * DEG)
#define HID 128
#define NF 128
#define TBL2 80
#define TROWS (TBL2 + 2)   // 82 stored rows (grid -1 .. 80)
#define PROWS 81           // pair rows s=0..80: (row s, row s+1)
#define CUTOFF 10.0f
#define LOG2F_ 0.6931471805599453f

typedef __attribute__((ext_vector_type(8))) short short8v;
typedef __attribute__((ext_vector_type(4))) float f32x4;
typedef __attribute__((ext_vector_type(2))) __bf16 bf16x2;
typedef unsigned short ushort_t;

__device__ __forceinline__ float ssp_f(float x) {
  float ax = fabsf(x);
  return fmaxf(x, 0.0f) + log1pf(expf(-ax)) - LOG2F_;
}
__device__ __forceinline__ ushort_t bf16rne(float x) {
  unsigned u = __float_as_uint(x);
  unsigned r = 0x7FFFu + ((u >> 16) & 1u);
  return (ushort_t)((u + r) >> 16);
}
__device__ __forceinline__ unsigned pk2(float a, float b) {
  return (unsigned)bf16rne(a) | ((unsigned)bf16rne(b) << 16);
}
__device__ __forceinline__ float bflo(unsigned u) { return __uint_as_float(u << 16); }
__device__ __forceinline__ float bfhi(unsigned u) { return __uint_as_float(u & 0xFFFF0000u); }
__device__ __forceinline__ int bidx(int row, int col) {
  return row * 128 + (col ^ ((row & 7) << 3));
}
__device__ __forceinline__ float fdot2b(unsigned a, unsigned b, float c) {
#if defined(__has_builtin) && __has_builtin(__builtin_amdgcn_fdot2_f32_bf16)
  return __builtin_amdgcn_fdot2_f32_bf16(__builtin_bit_cast(bf16x2, a),
                                         __builtin_bit_cast(bf16x2, b), c, false);
#else
  return fmaf(bflo(a), bflo(b), fmaf(bfhi(a), bfhi(b), c));
#endif
}

// ---- filter tables (3 layers) -> bf16 [TROWS][128]; 8 rows/block ----
__global__ void k_table(const float* __restrict__ w1_, const float* __restrict__ b1_,
                        const float* __restrict__ w2_, const float* __restrict__ b2_,
                        ushort_t* __restrict__ table_) {
  __shared__ float eaT[NF][8];
  __shared__ float hvT[NF][8];
  int l = blockIdx.y;
  const float* w1 = w1_ + (size_t)l * NF * NF;
  const float* b1 = b1_ + (size_t)l * NF;
  const float* w2 = w2_ + (size_t)l * NF * NF;
  const float* b2 = b2_ + (size_t)l * NF;
  ushort_t* table = table_ + (size_t)l * TROWS * NF;
  int j = threadIdx.x;
  int rbase = blockIdx.x * 8;
  const float hh = CUTOFF / (float)(TBL2 - 1);
  const float delta = CUTOFF / (float)(NF - 1);
  const float coeff = -0.5f / (delta * delta);
#pragma unroll
  for (int rr = 0; rr < 8; ++rr) {
    float d = ((float)(rbase + rr) - 1.0f) * hh;
    float tt = d - delta * (float)j;
    eaT[j][rr] = expf(coeff * tt * tt);
  }
  __syncthreads();
  float acc[8], wreg[16];
  float b1j = b1[j];
#pragma unroll
  for (int rr = 0; rr < 8; ++rr) acc[rr] = b1j;
  for (int kb = 0; kb < NF; kb += 16) {
#pragma unroll
    for (int i = 0; i < 16; ++i) wreg[i] = w1[(kb + i) * NF + j];
#pragma unroll
    for (int i = 0; i < 16; ++i) {
      float4 e0 = *(const float4*)&eaT[kb + i][0];
      float4 e1 = *(const float4*)&eaT[kb + i][4];
      float wv = wreg[i];
      acc[0] = fmaf(e0.x, wv, acc[0]); acc[1] = fmaf(e0.y, wv, acc[1]);
      acc[2] = fmaf(e0.z, wv, acc[2]); acc[3] = fmaf(e0.w, wv, acc[3]);
      acc[4] = fmaf(e1.x, wv, acc[4]); acc[5] = fmaf(e1.y, wv, acc[5]);
      acc[6] = fmaf(e1.z, wv, acc[6]); acc[7] = fmaf(e1.w, wv, acc[7]);
    }
  }
#pragma unroll
  for (int rr = 0; rr < 8; ++rr) hvT[j][rr] = ssp_f(acc[rr]);
  __syncthreads();
  float b2j = b2[j];
#pragma unroll
  for (int rr = 0; rr < 8; ++rr) acc[rr] = b2j;
  for (int kb = 0; kb < NF; kb += 16) {
#pragma unroll
    for (int i = 0; i < 16; ++i) wreg[i] = w2[(kb + i) * NF + j];
#pragma unroll
    for (int i = 0; i < 16; ++i) {
      float4 e0 = *(const float4*)&hvT[kb + i][0];
      float4 e1 = *(const float4*)&hvT[kb + i][4];
      float wv = wreg[i];
      acc[0] = fmaf(e0.x, wv, acc[0]); acc[1] = fmaf(e0.y, wv, acc[1]);
      acc[2] = fmaf(e0.z, wv, acc[2]); acc[3] = fmaf(e0.w, wv, acc[3]);
      acc[4] = fmaf(e1.x, wv, acc[4]); acc[5] = fmaf(e1.y, wv, acc[5]);
      acc[6] = fmaf(e1.z, wv, acc[6]); acc[7] = fmaf(e1.w, wv, acc[7]);
    }
  }
#pragma unroll
  for (int rr = 0; rr < 8; ++rr) {
    int s = rbase + rr;
    if (s < TROWS) {
      float d = ((float)s - 1.0f) * hh;
      float C = 0.5f * (cosf(d * (float)M_PI / CUTOFF) + 1.0f);
      table[(size_t)s * NF + j] = bf16rne(acc[rr] * C);
    }
  }
}

// ---- one-time: transpose + bf16 weights (9 GEMV mats + head hw1 -> slot 9) ----
__global__ void k_prep(const float* __restrict__ cf_w1, const float* __restrict__ cf_w2,
                       const float* __restrict__ lin_w, const float* __restrict__ hw1,
                       ushort_t* __restrict__ wtb) {
  __shared__ float tile[32][33];
  int b = blockIdx.x;
  int t = threadIdx.x;
  int tr = t >> 5, tc = t & 31;
  if (b < 36) {
    int m = b >> 2, tj = b & 3;
    int l = m / 3, ty = m % 3;
    const float* src = (ty == 0 ? cf_w1 : ty == 1 ? cf_w2 : lin_w) + (size_t)l * 128 * 128;
    ushort_t* dst = wtb + (size_t)m * 128 * 128;
    for (int ti = 0; ti < 4; ++ti) {
      __syncthreads();
#pragma unroll
      for (int i = 0; i < 4; ++i) {
        int r = tr + i * 8;
        tile[r][tc] = src[(ti * 32 + r) * 128 + tj * 32 + tc];
      }
      __syncthreads();
#pragma unroll
      for (int i = 0; i < 4; ++i) {
        int r = tr + i * 8;
        dst[(tj * 32 + r) * 128 + ti * 32 + tc] = bf16rne(tile[tc][r]);
      }
    }
  } else {
    int tj = b - 36;
    ushort_t* dst = wtb + (size_t)9 * 128 * 128;
    for (int ti = 0; ti < 4; ++ti) {
      __syncthreads();
#pragma unroll
      for (int i = 0; i < 4; ++i) {
        int r = tr + i * 8;
        tile[r][tc] = hw1[(ti * 32 + r) * 64 + tj * 32 + tc];
      }
      __syncthreads();
#pragma unroll
      for (int i = 0; i < 4; ++i) {
        int r = tr + i * 8;
        dst[(tj * 32 + r) * 128 + ti * 32 + tc] = bf16rne(tile[tc][r]);
      }
    }
  }
}

// ---- one-time: distances + cubic weights + CSR-by-destination; one uint4/edge ----
// ev = { pk2(w0,w1), pk2(w2,w3), i0*128, (r*64) | (((r&7)<<2)<<16) }
__global__ void __launch_bounds__(512) k_csr(const float* __restrict__ pos,
                                             const int* __restrict__ ei,
                                             uint4* __restrict__ ge,
                                             int* __restrict__ gstart) {
  __shared__ float spos[NPG * 3];
  __shared__ int cnt[NPG];
  __shared__ int pfx[NPG + 1];
  __shared__ uint4 epk[EPM];
  __shared__ unsigned char ecol[EPM];
  __shared__ short ssidx[EPM];
  int g = blockIdx.x, a0 = g * NPG, t = threadIdx.x;
  if (t < NPG * 3) spos[t] = pos[a0 * 3 + t];
  if (t < NPG) cnt[t] = 0;
  __syncthreads();
  int ebase = a0 * DEG;
  const float tscale = (float)(TBL2 - 1) / CUTOFF;
  for (int i = t; i < EPM; i += 512) {
    int r = ei[ebase + i] - a0;
    int c = ei[E_EDGES + ebase + i] - a0;
    float dx = spos[3 * r + 0] - spos[3 * c + 0];
    float dy = spos[3 * r + 1] - spos[3 * c + 1];
    float dz = spos[3 * r + 2] - spos[3 * c + 2];
    float ft = sqrtf(dx * dx + dy * dy + dz * dz) * tscale;
    int i0 = min((int)ft, TBL2 - 2);
    float tt = ft - (float)i0;
    float t2 = tt * tt, t3 = t2 * tt;
    float w0 = 0.5f * (-t3 + 2.f * t2 - tt);
    float w1 = 0.5f * (3.f * t3 - 5.f * t2 + 2.f);
    float w2 = 0.5f * (-3.f * t3 + 4.f * t2 + tt);
    float w3 = 0.5f * (t3 - t2);
    epk[i] = make_uint4(pk2(w0, w1), pk2(w2, w3), (unsigned)(i0 << 7),
                        (unsigned)((r << 6) | (((r & 7) << 2) << 16)));
    ecol[i] = (unsigned char)c;
    atomicAdd(&cnt[c], 1);
  }
  __syncthreads();
  if (t == 0) {
    int s = 0;
    for (int a = 0; a < NPG; ++a) { pfx[a] = s; s += cnt[a]; }
    pfx[NPG] = s;
  }
  __syncthreads();
  int w = t >> 6, lane = t & 63;
  for (int a = w * 5; a < w * 5 + 5; ++a) {
    int p = pfx[a];
#pragma unroll
    for (int ch = 0; ch < EPM / 64; ++ch) {
      int e = ch * 64 + lane;
      bool match = ((int)ecol[e] == a);
      unsigned long long bal = __ballot(match);
      if (match) ssidx[p + __popcll(bal & ((1ull << lane) - 1ull))] = (short)e;
      p += __popcll(bal);
    }
  }
  __syncthreads();
  for (int i = t; i < EPM; i += 512) ge[(size_t)g * EPM + i] = epk[ssidx[i]];
  if (t < NPG) gstart[g * NPG + t] = pfx[t];
}

// ---------------- whole model per molecule ----------------
__global__ void __launch_bounds__(512) k_mol(
    const float* __restrict__ emb, const int* __restrict__ z,
    const uint4* __restrict__ ge, const int* __restrict__ gstart,
    const ushort_t* __restrict__ tblb, const ushort_t* __restrict__ wtb,
    const float* __restrict__ cf_b2, const float* __restrict__ lin_b,
    const float* __restrict__ hb1, const float* __restrict__ hw2,
    const float* __restrict__ hb2, float* __restrict__ out) {
  __shared__ unsigned ptab[PROWS * 128];  // 41,472 B pair-packed table
  __shared__ ushort_t sb0[48 * 128];      // 12,288 B
  __shared__ ushort_t sb1[48 * 128];      // 12,288 B
  __shared__ uint4 sedge[EPM];            // 10,240 B
  __shared__ int sstart[NPG + 1];
  __shared__ float shead[48];
  __shared__ int sz[NPG];
  int g = blockIdx.x, a0 = g * NPG, t = threadIdx.x;
  int w = t >> 6, l6 = t & 63, r15 = l6 & 15, q = l6 >> 4;
  int colo = w * 16 + r15;
  int half = l6 >> 5, li = l6 & 31, ch0 = li * 4;  // edge-pair mapping

  // ---- stage ----
  {
    if (t < NPG) sz[t] = z[a0 + t];
    const uint4* gsrc = ge + (size_t)g * EPM;
    for (int i = t; i < EPM; i += 512) sedge[i] = gsrc[i];
    if (t < NPG) sstart[t] = gstart[g * NPG + t];
    if (t == 0) sstart[NPG] = EPM;
    if (t < 48) shead[t] = 0.f;
    ((unsigned*)sb0)[40 * 64 + t] = 0u;  // zero pad rows 40..47
    ((unsigned*)sb1)[40 * 64 + t] = 0u;
    const ushort_t* tg = tblb;
    for (int i = t; i < PROWS * 32; i += 512) {
      int s = i >> 5, c4 = (i & 31) << 2;
      uint2 ar = *(const uint2*)(tg + s * 128 + c4);
      uint2 br = *(const uint2*)(tg + (s + 1) * 128 + c4);
      uint4 o;
      o.x = (ar.x & 0xffffu) | (br.x << 16);
      o.y = (ar.x >> 16) | (br.x & 0xffff0000u);
      o.z = (ar.y & 0xffffu) | (br.y << 16);
      o.w = (ar.y >> 16) | (br.y & 0xffff0000u);
      *(uint4*)&ptab[(s << 7) + c4] = o;
    }
  }
  __syncthreads();

  // ---- h init from embedding: fragment registers + sb0 bf16 ----
  float hreg[12];
#pragma unroll
  for (int mt = 0; mt < 3; ++mt) {
#pragma unroll
    for (int r = 0; r < 4; ++r) {
      int row = mt * 16 + q * 4 + r;
      float v = 0.f;
      if (row < NPG) {
        v = emb[(size_t)sz[row] * HID + colo];
        sb0[bidx(row, colo)] = bf16rne(v);
      }
      hreg[mt * 4 + r] = v;
    }
  }
  __syncthreads();

  for (int l = 0; l < 3; ++l) {
    const ushort_t* w1t = wtb + (size_t)(l * 3 + 0) * 128 * 128;
    const ushort_t* w2t = wtb + (size_t)(l * 3 + 1) * 128 * 128;
    const ushort_t* lwt = wtb + (size_t)(l * 3 + 2) * 128 * 128;
    if (l > 0) {
      const ushort_t* tg = tblb + (size_t)l * TROWS * 128;
      for (int i = t; i < PROWS * 32; i += 512) {
        int s = i >> 5, c4 = (i & 31) << 2;
        uint2 ar = *(const uint2*)(tg + s * 128 + c4);
        uint2 br = *(const uint2*)(tg + (s + 1) * 128 + c4);
        uint4 o;
        o.x = (ar.x & 0xffffu) | (br.x << 16);
        o.y = (ar.x >> 16) | (br.x & 0xffff0000u);
        o.z = (ar.y & 0xffffu) | (br.y << 16);
        o.w = (ar.y >> 16) | (br.y & 0xffff0000u);
        *(uint4*)&ptab[(s << 7) + c4] = o;
      }
    }
    // ---- GEMV1: x1 = h @ w1  (sb0 -> sb1) ----
    {
      short8v bfr[4];
      const ushort_t* wp = w1t + (size_t)colo * 128 + q * 8;
#pragma unroll
      for (int ks = 0; ks < 4; ++ks) bfr[ks] = *(const short8v*)(wp + ks * 32);
#pragma unroll
      for (int mt = 0; mt < 3; ++mt) {
        f32x4 acc = (f32x4){0.f, 0.f, 0.f, 0.f};
#pragma unroll
        for (int ks = 0; ks < 4; ++ks) {
          short8v af = *(const short8v*)&sb0[bidx(mt * 16 + r15, ks * 32 + q * 8)];
          acc = __builtin_amdgcn_mfma_f32_16x16x32_bf16(af, bfr[ks], acc, 0, 0, 0);
        }
#pragma unroll
        for (int r = 0; r < 4; ++r) sb1[bidx(mt * 16 + q * 4 + r, colo)] = bf16rne(acc[r]);
      }
    }
    __syncthreads();
    // ---- edge agg: half-wave edge pairing, 4 ch/lane (sb1 -> sb0) ----
    {
      const unsigned* b1u = (const unsigned*)sb1;
      unsigned* b0u = (unsigned*)sb0;
      for (int a = w; a < NPG; a += 8) {
        int kb = sstart[a], ke = sstart[a + 1];
        float a0c = 0.f, a1c = 0.f, a2c = 0.f, a3c = 0.f;
        for (int k = kb; k < ke; k += 2) {
          int idx = k + half;
          uint4 ev = sedge[min(idx, EPM - 1)];
          bool ok = idx < ke;
          unsigned w01 = ok ? ev.x : 0u;
          unsigned w23 = ok ? ev.y : 0u;
          const unsigned* tb = ptab + ev.z + ch0;
          uint4 pa = *(const uint4*)tb;
          uint4 pb = *(const uint4*)(tb + 256);
          uint2 xv = *(const uint2*)&b1u[(ev.w & 0xffffu) + ((li * 2) ^ (ev.w >> 16))];
          float f0 = fdot2b(w01, pa.x, 0.f); f0 = fdot2b(w23, pb.x, f0);
          float f1 = fdot2b(w01, pa.y, 0.f); f1 = fdot2b(w23, pb.y, f1);
          float f2 = fdot2b(w01, pa.z, 0.f); f2 = fdot2b(w23, pb.z, f2);
          float f3 = fdot2b(w01, pa.w, 0.f); f3 = fdot2b(w23, pb.w, f3);
          a0c = fmaf(bflo(xv.x), f0, a0c);
          a1c = fmaf(bfhi(xv.x), f1, a1c);
          a2c = fmaf(bflo(xv.y), f2, a2c);
          a3c = fmaf(bfhi(xv.y), f3, a3c);
        }
        a0c += __shfl_xor(a0c, 32);
        a1c += __shfl_xor(a1c, 32);
        a2c += __shfl_xor(a2c, 32);
        a3c += __shfl_xor(a3c, 32);
        if (half == 0) {
          uint2 o;
          o.x = pk2(a0c, a1c);
          o.y = pk2(a2c, a3c);
          *(uint2*)&b0u[(a << 6) + ((li * 2) ^ ((a & 7) << 2))] = o;
        }
      }
    }
    __syncthreads();
    // ---- GEMV2: u = ssp(agg @ w2 + b2)  (sb0 -> sb1) ----
    {
      float bc = cf_b2[(size_t)l * HID + colo];
      short8v bfr[4];
      const ushort_t* wp = w2t + (size_t)colo * 128 + q * 8;
#pragma unroll
      for (int ks = 0; ks < 4; ++ks) bfr[ks] = *(const short8v*)(wp + ks * 32);
#pragma unroll
      for (int mt = 0; mt < 3; ++mt) {
        f32x4 acc = (f32x4){0.f, 0.f, 0.f, 0.f};
#pragma unroll
        for (int ks = 0; ks < 4; ++ks) {
          short8v af = *(const short8v*)&sb0[bidx(mt * 16 + r15, ks * 32 + q * 8)];
          acc = __builtin_amdgcn_mfma_f32_16x16x32_bf16(af, bfr[ks], acc, 0, 0, 0);
        }
#pragma unroll
        for (int r = 0; r < 4; ++r) {
          int row = mt * 16 + q * 4 + r;
          float v = (row < NPG) ? ssp_f(acc[r] + bc) : 0.f;
          sb1[bidx(row, colo)] = bf16rne(v);
        }
      }
    }
    __syncthreads();
    // ---- GEMV3: h += u @ lw + lb  (sb1 -> hreg + sb0 bf16) ----
    {
      float bc = lin_b[(size_t)l * HID + colo];
      short8v bfr[4];
      const ushort_t* wp = lwt + (size_t)colo * 128 + q * 8;
#pragma unroll
      for (int ks = 0; ks < 4; ++ks) bfr[ks] = *(const short8v*)(wp + ks * 32);
#pragma unroll
      for (int mt = 0; mt < 3; ++mt) {
        f32x4 acc = (f32x4){0.f, 0.f, 0.f, 0.f};
#pragma unroll
        for (int ks = 0; ks < 4; ++ks) {
          short8v af = *(const short8v*)&sb1[bidx(mt * 16 + r15, ks * 32 + q * 8)];
          acc = __builtin_amdgcn_mfma_f32_16x16x32_bf16(af, bfr[ks], acc, 0, 0, 0);
        }
#pragma unroll
        for (int r = 0; r < 4; ++r) {
          int row = mt * 16 + q * 4 + r;
          if (row < NPG) {
            float nh = hreg[mt * 4 + r] + acc[r] + bc;
            hreg[mt * 4 + r] = nh;
            sb0[bidx(row, colo)] = bf16rne(nh);
          }
        }
      }
    }
    __syncthreads();
  }

  // ---- head via MFMA: y = ssp(H@hw1+hb1)@hw2; out[g] = sum + 40*hb2 ----
  {
    const ushort_t* h1t = wtb + (size_t)9 * 128 * 128;
    for (int tile = w; tile < 12; tile += 8) {
      int mt = tile >> 2, nt = tile & 3;
      int col = nt * 16 + r15;
      short8v bfr[4];
      const ushort_t* wp = h1t + (size_t)col * 128 + q * 8;
#pragma unroll
      for (int ks = 0; ks < 4; ++ks) bfr[ks] = *(const short8v*)(wp + ks * 32);
      f32x4 acc = (f32x4){0.f, 0.f, 0.f, 0.f};
#pragma unroll
      for (int ks = 0; ks < 4; ++ks) {
        short8v af = *(const short8v*)&sb0[bidx(mt * 16 + r15, ks * 32 + q * 8)];
        acc = __builtin_amdgcn_mfma_f32_16x16x32_bf16(af, bfr[ks], acc, 0, 0, 0);
      }
      float hb = hb1[col];
      float w2v = hw2[col];
#pragma unroll
      for (int r = 0; r < 4; ++r) {
        int row = mt * 16 + q * 4 + r;
        float y = ssp_f(acc[r] + hb) * w2v;
        y += __shfl_xor(y, 1);
        y += __shfl_xor(y, 2);
        y += __shfl_xor(y, 4);
        y += __shfl_xor(y, 8);
        if (r15 == 0 && row < NPG) atomicAdd(&shead[row], y);
      }
    }
  }
  __syncthreads();
  if (w == 0) {
    float v = (l6 < NPG) ? shead[l6] : 0.f;
#pragma unroll
    for (int off = 32; off; off >>= 1) v += __shfl_xor(v, off);
    if (l6 == 0) out[g] = v + (float)NPG * hb2[0];
  }
}

extern "C" void kernel_launch(void* const* d_in, const int* in_sizes, int n_in,
                              void* d_out, int out_size, void* d_ws, size_t ws_size,
                              hipStream_t stream) {
  const float* pos    = (const float*)d_in[0];
  const float* emb    = (const float*)d_in[1];
  const float* mlp_w1 = (const float*)d_in[2];
  const float* mlp_b1 = (const float*)d_in[3];
  const float* mlp_w2 = (const float*)d_in[4];
  const float* mlp_b2 = (const float*)d_in[5];
  const float* cf_w1  = (const float*)d_in[6];
  const float* cf_w2  = (const float*)d_in[7];
  const float* cf_b2  = (const float*)d_in[8];
  const float* lin_w  = (const float*)d_in[9];
  const float* lin_b  = (const float*)d_in[10];
  const float* hw1    = (const float*)d_in[11];
  const float* hb1    = (const float*)d_in[12];
  const float* hw2    = (const float*)d_in[13];
  const float* hb2    = (const float*)d_in[14];
  const int*   z      = (const int*)d_in[15];
  const int*   ei     = (const int*)d_in[17];

  char* wsb = (char*)d_ws;
  uint4*    ge     = (uint4*)wsb;                       // E*16 = 5,120,000
  int*      gstart = (int*)(wsb + 5120000);             // 80,000
  ushort_t* tblb   = (ushort_t*)(wsb + 5200000);        // 3*82*128*2 = 62,976
  ushort_t* wtb    = (ushort_t*)(wsb + 5262976);        // 10*16384*2 = 327,680
  size_t need = 5262976 + 327680;
  if (ws_size < need) return;

  k_table<<<dim3((TROWS + 7) / 8, 3), NF, 0, stream>>>(mlp_w1, mlp_b1, mlp_w2, mlp_b2, tblb);
  k_prep<<<38, 256, 0, stream>>>(cf_w1, cf_w2, lin_w, hw1, wtb);
  k_csr<<<G_GRAPHS, 512, 0, stream>>>(pos, ei, ge, gstart);
  k_mol<<<G_GRAPHS, 512, 0, stream>>>(emb, z, ge, gstart, tblb, wtb,
                                      cf_b2, lin_b, hb1, hw2, hb2, (float*)d_out);
}

// Round 13
// 104.921 us; speedup vs baseline: 3.6949x; 1.0810x over previous
//
#include <hip/hip_runtime.h>
#include <math.h>

#define N_ATOMS 20000
#define G_GRAPHS 500
#define NPG 40
#define DEG 16
#define E_EDGES (N_ATOMS * DEG)
#define EPM (NPG * DEG)          // 640 real edges per molecule
#define EPAD 680                 // padded capacity (each atom even count)
#define HID 128
#define NF 128
#define TBL2 80
#define TROWS (TBL2 + 2)         // 82 stored rows (grid -1 .. 80)
#define PROWS 81                 // pair rows s=0..80: (row s, row s+1)
#define CUTOFF 10.0f
#define LOG2F_ 0.6931471805599453f

typedef __attribute__((ext_vector_type(8))) short short8v;
typedef __attribute__((ext_vector_type(4))) float f32x4;
typedef __attribute__((ext_vector_type(2))) __bf16 bf16x2;
typedef unsigned short ushort_t;

__device__ __forceinline__ float ssp_f(float x) {
  float ax = fabsf(x);
  return fmaxf(x, 0.0f) + log1pf(expf(-ax)) - LOG2F_;
}
__device__ __forceinline__ ushort_t bf16rne(float x) {
  unsigned u = __float_as_uint(x);
  unsigned r = 0x7FFFu + ((u >> 16) & 1u);
  return (ushort_t)((u + r) >> 16);
}
__device__ __forceinline__ unsigned pk2(float a, float b) {
  return (unsigned)bf16rne(a) | ((unsigned)bf16rne(b) << 16);
}
__device__ __forceinline__ float bflo(unsigned u) { return __uint_as_float(u << 16); }
__device__ __forceinline__ float bfhi(unsigned u) { return __uint_as_float(u & 0xFFFF0000u); }
__device__ __forceinline__ int bidx(int row, int col) {
  return row * 128 + (col ^ ((row & 7) << 3));
}
__device__ __forceinline__ float fdot2b(unsigned a, unsigned b, float c) {
#if defined(__has_builtin) && __has_builtin(__builtin_amdgcn_fdot2_f32_bf16)
  return __builtin_amdgcn_fdot2_f32_bf16(__builtin_bit_cast(bf16x2, a),
                                         __builtin_bit_cast(bf16x2, b), c, false);
#else
  return fmaf(bflo(a), bflo(b), fmaf(bfhi(a), bfhi(b), c));
#endif
}

// ================= merged preamble: table(33) | prep(38) | csr(500) =================
__global__ void __launch_bounds__(512) k_pre(
    const float* __restrict__ mlp_w1, const float* __restrict__ mlp_b1,
    const float* __restrict__ mlp_w2, const float* __restrict__ mlp_b2,
    const float* __restrict__ cf_w1, const float* __restrict__ cf_w2,
    const float* __restrict__ lin_w, const float* __restrict__ hw1,
    const float* __restrict__ pos, const int* __restrict__ ei,
    unsigned* __restrict__ ptabg, ushort_t* __restrict__ wtb,
    uint4* __restrict__ ge, int* __restrict__ gstart) {
  int b = blockIdx.x;
  int t = threadIdx.x;

  if (b < 33) {
    // ---------- filter-table role: 8 rows per block, pair-packed global output ----------
    __shared__ float eaT[NF][8];
    __shared__ float hvT[NF][8];
    int l = b / 11;
    int rbase = (b % 11) * 8;
    const float* w1 = mlp_w1 + (size_t)l * NF * NF;
    const float* b1 = mlp_b1 + (size_t)l * NF;
    const float* w2 = mlp_w2 + (size_t)l * NF * NF;
    const float* b2 = mlp_b2 + (size_t)l * NF;
    ushort_t* pp = (ushort_t*)(ptabg + (size_t)l * PROWS * 128);
    const float hh = CUTOFF / (float)(TBL2 - 1);
    const float delta = CUTOFF / (float)(NF - 1);
    const float coeff = -0.5f / (delta * delta);
    int j = t & 127;
    bool act = t < 128;
    if (act) {
#pragma unroll
      for (int rr = 0; rr < 8; ++rr) {
        float d = ((float)(rbase + rr) - 1.0f) * hh;
        float tt = d - delta * (float)j;
        eaT[j][rr] = expf(coeff * tt * tt);
      }
    }
    __syncthreads();
    float acc[8], wreg[16];
    if (act) {
      float b1j = b1[j];
#pragma unroll
      for (int rr = 0; rr < 8; ++rr) acc[rr] = b1j;
      for (int kb = 0; kb < NF; kb += 16) {
#pragma unroll
        for (int i = 0; i < 16; ++i) wreg[i] = w1[(kb + i) * NF + j];
#pragma unroll
        for (int i = 0; i < 16; ++i) {
          float4 e0 = *(const float4*)&eaT[kb + i][0];
          float4 e1 = *(const float4*)&eaT[kb + i][4];
          float wv = wreg[i];
          acc[0] = fmaf(e0.x, wv, acc[0]); acc[1] = fmaf(e0.y, wv, acc[1]);
          acc[2] = fmaf(e0.z, wv, acc[2]); acc[3] = fmaf(e0.w, wv, acc[3]);
          acc[4] = fmaf(e1.x, wv, acc[4]); acc[5] = fmaf(e1.y, wv, acc[5]);
          acc[6] = fmaf(e1.z, wv, acc[6]); acc[7] = fmaf(e1.w, wv, acc[7]);
        }
      }
#pragma unroll
      for (int rr = 0; rr < 8; ++rr) hvT[j][rr] = ssp_f(acc[rr]);
    }
    __syncthreads();
    if (act) {
      float b2j = b2[j];
#pragma unroll
      for (int rr = 0; rr < 8; ++rr) acc[rr] = b2j;
      for (int kb = 0; kb < NF; kb += 16) {
#pragma unroll
        for (int i = 0; i < 16; ++i) wreg[i] = w2[(kb + i) * NF + j];
#pragma unroll
        for (int i = 0; i < 16; ++i) {
          float4 e0 = *(const float4*)&hvT[kb + i][0];
          float4 e1 = *(const float4*)&hvT[kb + i][4];
          float wv = wreg[i];
          acc[0] = fmaf(e0.x, wv, acc[0]); acc[1] = fmaf(e0.y, wv, acc[1]);
          acc[2] = fmaf(e0.z, wv, acc[2]); acc[3] = fmaf(e0.w, wv, acc[3]);
          acc[4] = fmaf(e1.x, wv, acc[4]); acc[5] = fmaf(e1.y, wv, acc[5]);
          acc[6] = fmaf(e1.z, wv, acc[6]); acc[7] = fmaf(e1.w, wv, acc[7]);
        }
      }
#pragma unroll
      for (int rr = 0; rr < 8; ++rr) {
        int s = rbase + rr;
        if (s < TROWS) {
          float d = ((float)s - 1.0f) * hh;
          float C = 0.5f * (cosf(d * (float)M_PI / CUTOFF) + 1.0f);
          ushort_t v = bf16rne(acc[rr] * C);
          if (s < PROWS) pp[(s * 128 + j) * 2] = v;          // low half of pair s
          if (s >= 1) pp[((s - 1) * 128 + j) * 2 + 1] = v;   // high half of pair s-1
        }
      }
    }
  } else if (b < 71) {
    // ---------- weight transpose role ----------
    __shared__ float tile[32][33];
    int pb = b - 33;
    int tr = (t & 255) >> 5, tc = t & 31;
    bool act = t < 256;
    if (pb < 36) {
      int m = pb >> 2, tj = pb & 3;
      int l = m / 3, ty = m % 3;
      const float* src = (ty == 0 ? cf_w1 : ty == 1 ? cf_w2 : lin_w) + (size_t)l * 128 * 128;
      ushort_t* dst = wtb + (size_t)m * 128 * 128;
      for (int ti = 0; ti < 4; ++ti) {
        __syncthreads();
        if (act) {
#pragma unroll
          for (int i = 0; i < 4; ++i) {
            int r = tr + i * 8;
            tile[r][tc] = src[(ti * 32 + r) * 128 + tj * 32 + tc];
          }
        }
        __syncthreads();
        if (act) {
#pragma unroll
          for (int i = 0; i < 4; ++i) {
            int r = tr + i * 8;
            dst[(tj * 32 + r) * 128 + ti * 32 + tc] = bf16rne(tile[tc][r]);
          }
        }
      }
    } else {
      int tj = pb - 36;
      ushort_t* dst = wtb + (size_t)9 * 128 * 128;
      for (int ti = 0; ti < 4; ++ti) {
        __syncthreads();
        if (act) {
#pragma unroll
          for (int i = 0; i < 4; ++i) {
            int r = tr + i * 8;
            tile[r][tc] = hw1[(ti * 32 + r) * 64 + tj * 32 + tc];
          }
        }
        __syncthreads();
        if (act) {
#pragma unroll
          for (int i = 0; i < 4; ++i) {
            int r = tr + i * 8;
            dst[(tj * 32 + r) * 128 + ti * 32 + tc] = bf16rne(tile[tc][r]);
          }
        }
      }
    }
  } else {
    // ---------- CSR role: distances + cubic weights + even-padded CSR ----------
    __shared__ float spos[NPG * 3];
    __shared__ int cnt[NPG];
    __shared__ int pfx[NPG + 1];
    __shared__ uint4 epk[EPM];
    __shared__ unsigned char ecol[EPM];
    __shared__ short ssidx[EPAD];
    int g = b - 71, a0 = g * NPG;
    if (t < NPG * 3) spos[t] = pos[a0 * 3 + t];
    if (t < NPG) cnt[t] = 0;
    for (int i = t; i < EPAD; i += 512) ssidx[i] = -1;
    __syncthreads();
    int ebase = a0 * DEG;
    const float tscale = (float)(TBL2 - 1) / CUTOFF;
    for (int i = t; i < EPM; i += 512) {
      int r = ei[ebase + i] - a0;
      int c = ei[E_EDGES + ebase + i] - a0;
      float dx = spos[3 * r + 0] - spos[3 * c + 0];
      float dy = spos[3 * r + 1] - spos[3 * c + 1];
      float dz = spos[3 * r + 2] - spos[3 * c + 2];
      float ft = sqrtf(dx * dx + dy * dy + dz * dz) * tscale;
      int i0 = min((int)ft, TBL2 - 2);
      float tt = ft - (float)i0;
      float t2 = tt * tt, t3 = t2 * tt;
      float w0 = 0.5f * (-t3 + 2.f * t2 - tt);
      float w1 = 0.5f * (3.f * t3 - 5.f * t2 + 2.f);
      float w2 = 0.5f * (-3.f * t3 + 4.f * t2 + tt);
      float w3 = 0.5f * (t3 - t2);
      epk[i] = make_uint4(pk2(w0, w1), pk2(w2, w3), (unsigned)(i0 << 7),
                          (unsigned)((r << 6) | (((r & 7) << 2) << 16)));
      ecol[i] = (unsigned char)c;
      atomicAdd(&cnt[c], 1);
    }
    __syncthreads();
    if (t == 0) {
      int s = 0;
      for (int a = 0; a < NPG; ++a) { pfx[a] = s; s += (cnt[a] + 1) & ~1; }
      pfx[NPG] = s;
    }
    __syncthreads();
    int w = t >> 6, lane = t & 63;
    for (int a = w * 5; a < w * 5 + 5; ++a) {
      int p = pfx[a];
#pragma unroll
      for (int ch = 0; ch < EPM / 64; ++ch) {
        int e = ch * 64 + lane;
        bool match = ((int)ecol[e] == a);
        unsigned long long bal = __ballot(match);
        if (match) ssidx[p + __popcll(bal & ((1ull << lane) - 1ull))] = (short)e;
        p += __popcll(bal);
      }
    }
    __syncthreads();
    int ptot = pfx[NPG];
    const uint4 z4 = make_uint4(0u, 0u, 0u, 0u);
    for (int i = t; i < ptot; i += 512) {
      int e = ssidx[i];
      ge[(size_t)g * EPAD + i] = (e >= 0) ? epk[e] : z4;
    }
    if (t <= NPG) gstart[g * (NPG + 1) + t] = pfx[t];
  }
}

// ================= whole model per molecule =================
__global__ void __launch_bounds__(512) k_mol(
    const float* __restrict__ emb, const int* __restrict__ z,
    const uint4* __restrict__ ge, const int* __restrict__ gstart,
    const unsigned* __restrict__ ptabg, const ushort_t* __restrict__ wtb,
    const float* __restrict__ cf_b2, const float* __restrict__ lin_b,
    const float* __restrict__ hb1, const float* __restrict__ hw2,
    const float* __restrict__ hb2, float* __restrict__ out) {
  __shared__ unsigned ptab[PROWS * 128];  // 41,472 B pair-packed table
  __shared__ ushort_t sb0[48 * 128];      // 12,288 B
  __shared__ ushort_t sb1[48 * 128];      // 12,288 B
  __shared__ uint4 sedge[EPAD];           // 10,880 B
  __shared__ int sstart[NPG + 1];
  __shared__ float shead[48];
  __shared__ int sz[NPG];
  int g = blockIdx.x, a0 = g * NPG, t = threadIdx.x;
  int w = t >> 6, l6 = t & 63, r15 = l6 & 15, q = l6 >> 4;
  int colo = w * 16 + r15;
  int half = l6 >> 5, li = l6 & 31, ch0 = li * 4;

  // ---- stage ----
  int ptot = gstart[g * (NPG + 1) + NPG];
  {
    if (t < NPG) sz[t] = z[a0 + t];
    if (t <= NPG) sstart[t] = gstart[g * (NPG + 1) + t];
    const uint4* gsrc = ge + (size_t)g * EPAD;
    for (int i = t; i < ptot; i += 512) sedge[i] = gsrc[i];
    if (t < 48) shead[t] = 0.f;
    ((unsigned*)sb0)[40 * 64 + t] = 0u;  // zero pad rows 40..47
    ((unsigned*)sb1)[40 * 64 + t] = 0u;
    const uint4* tg4 = (const uint4*)ptabg;
    uint4* st4 = (uint4*)ptab;
    for (int i = t; i < PROWS * 32; i += 512) st4[i] = tg4[i];
  }
  __syncthreads();

  // ---- h init from embedding: fragment registers + sb0 bf16 ----
  float hreg[12];
#pragma unroll
  for (int mt = 0; mt < 3; ++mt) {
#pragma unroll
    for (int r = 0; r < 4; ++r) {
      int row = mt * 16 + q * 4 + r;
      float v = 0.f;
      if (row < NPG) {
        v = emb[(size_t)sz[row] * HID + colo];
        sb0[bidx(row, colo)] = bf16rne(v);
      }
      hreg[mt * 4 + r] = v;
    }
  }
  __syncthreads();

  for (int l = 0; l < 3; ++l) {
    const ushort_t* w1t = wtb + (size_t)(l * 3 + 0) * 128 * 128;
    const ushort_t* w2t = wtb + (size_t)(l * 3 + 1) * 128 * 128;
    const ushort_t* lwt = wtb + (size_t)(l * 3 + 2) * 128 * 128;
    if (l > 0) {  // restage pre-packed pair table (pure copy)
      const uint4* tg4 = (const uint4*)(ptabg + (size_t)l * PROWS * 128);
      uint4* st4 = (uint4*)ptab;
      for (int i = t; i < PROWS * 32; i += 512) st4[i] = tg4[i];
    }
    // ---- GEMV1: x1 = h @ w1  (sb0 -> sb1) ----
    {
      short8v bfr[4];
      const ushort_t* wp = w1t + (size_t)colo * 128 + q * 8;
#pragma unroll
      for (int ks = 0; ks < 4; ++ks) bfr[ks] = *(const short8v*)(wp + ks * 32);
#pragma unroll
      for (int mt = 0; mt < 3; ++mt) {
        f32x4 acc = (f32x4){0.f, 0.f, 0.f, 0.f};
#pragma unroll
        for (int ks = 0; ks < 4; ++ks) {
          short8v af = *(const short8v*)&sb0[bidx(mt * 16 + r15, ks * 32 + q * 8)];
          acc = __builtin_amdgcn_mfma_f32_16x16x32_bf16(af, bfr[ks], acc, 0, 0, 0);
        }
#pragma unroll
        for (int r = 0; r < 4; ++r) sb1[bidx(mt * 16 + q * 4 + r, colo)] = bf16rne(acc[r]);
      }
    }
    __syncthreads();
    // ---- edge agg: half-wave edge pairing, even-padded (sb1 -> sb0) ----
    {
      const unsigned* b1u = (const unsigned*)sb1;
      unsigned* b0u = (unsigned*)sb0;
      for (int a = w; a < NPG; a += 8) {
        int kb = sstart[a], ke = sstart[a + 1];
        float a0c = 0.f, a1c = 0.f, a2c = 0.f, a3c = 0.f;
        for (int k = kb + half; k < ke; k += 2) {
          uint4 ev = sedge[k];
          const unsigned* tb = ptab + ev.z + ch0;
          uint4 pa = *(const uint4*)tb;
          uint4 pb = *(const uint4*)(tb + 256);
          uint2 xv = *(const uint2*)&b1u[(ev.w & 0xffffu) + ((li * 2) ^ (ev.w >> 16))];
          float f0 = fdot2b(ev.x, pa.x, 0.f); f0 = fdot2b(ev.y, pb.x, f0);
          float f1 = fdot2b(ev.x, pa.y, 0.f); f1 = fdot2b(ev.y, pb.y, f1);
          float f2 = fdot2b(ev.x, pa.z, 0.f); f2 = fdot2b(ev.y, pb.z, f2);
          float f3 = fdot2b(ev.x, pa.w, 0.f); f3 = fdot2b(ev.y, pb.w, f3);
          a0c = fmaf(bflo(xv.x), f0, a0c);
          a1c = fmaf(bfhi(xv.x), f1, a1c);
          a2c = fmaf(bflo(xv.y), f2, a2c);
          a3c = fmaf(bfhi(xv.y), f3, a3c);
        }
        a0c += __shfl_xor(a0c, 32);
        a1c += __shfl_xor(a1c, 32);
        a2c += __shfl_xor(a2c, 32);
        a3c += __shfl_xor(a3c, 32);
        if (half == 0) {
          uint2 o;
          o.x = pk2(a0c, a1c);
          o.y = pk2(a2c, a3c);
          *(uint2*)&b0u[(a << 6) + ((li * 2) ^ ((a & 7) << 2))] = o;
        }
      }
    }
    __syncthreads();
    // ---- GEMV2: u = ssp(agg @ w2 + b2)  (sb0 -> sb1) ----
    {
      float bc = cf_b2[(size_t)l * HID + colo];
      short8v bfr[4];
      const ushort_t* wp = w2t + (size_t)colo * 128 + q * 8;
#pragma unroll
      for (int ks = 0; ks < 4; ++ks) bfr[ks] = *(const short8v*)(wp + ks * 32);
#pragma unroll
      for (int mt = 0; mt < 3; ++mt) {
        f32x4 acc = (f32x4){0.f, 0.f, 0.f, 0.f};
#pragma unroll
        for (int ks = 0; ks < 4; ++ks) {
          short8v af = *(const short8v*)&sb0[bidx(mt * 16 + r15, ks * 32 + q * 8)];
          acc = __builtin_amdgcn_mfma_f32_16x16x32_bf16(af, bfr[ks], acc, 0, 0, 0);
        }
#pragma unroll
        for (int r = 0; r < 4; ++r) {
          int row = mt * 16 + q * 4 + r;
          float v = (row < NPG) ? ssp_f(acc[r] + bc) : 0.f;
          sb1[bidx(row, colo)] = bf16rne(v);
        }
      }
    }
    __syncthreads();
    // ---- GEMV3: h += u @ lw + lb  (sb1 -> hreg + sb0 bf16) ----
    {
      float bc = lin_b[(size_t)l * HID + colo];
      short8v bfr[4];
      const ushort_t* wp = lwt + (size_t)colo * 128 + q * 8;
#pragma unroll
      for (int ks = 0; ks < 4; ++ks) bfr[ks] = *(const short8v*)(wp + ks * 32);
#pragma unroll
      for (int mt = 0; mt < 3; ++mt) {
        f32x4 acc = (f32x4){0.f, 0.f, 0.f, 0.f};
#pragma unroll
        for (int ks = 0; ks < 4; ++ks) {
          short8v af = *(const short8v*)&sb1[bidx(mt * 16 + r15, ks * 32 + q * 8)];
          acc = __builtin_amdgcn_mfma_f32_16x16x32_bf16(af, bfr[ks], acc, 0, 0, 0);
        }
#pragma unroll
        for (int r = 0; r < 4; ++r) {
          int row = mt * 16 + q * 4 + r;
          if (row < NPG) {
            float nh = hreg[mt * 4 + r] + acc[r] + bc;
            hreg[mt * 4 + r] = nh;
            sb0[bidx(row, colo)] = bf16rne(nh);
          }
        }
      }
    }
    __syncthreads();
  }

  // ---- head via MFMA: y = ssp(H@hw1+hb1)@hw2; out[g] = sum + 40*hb2 ----
  {
    const ushort_t* h1t = wtb + (size_t)9 * 128 * 128;
    for (int tile = w; tile < 12; tile += 8) {
      int mt = tile >> 2, nt = tile & 3;
      int col = nt * 16 + r15;
      short8v bfr[4];
      const ushort_t* wp = h1t + (size_t)col * 128 + q * 8;
#pragma unroll
      for (int ks = 0; ks < 4; ++ks) bfr[ks] = *(const short8v*)(wp + ks * 32);
      f32x4 acc = (f32x4){0.f, 0.f, 0.f, 0.f};
#pragma unroll
      for (int ks = 0; ks < 4; ++ks) {
        short8v af = *(const short8v*)&sb0[bidx(mt * 16 + r15, ks * 32 + q * 8)];
        acc = __builtin_amdgcn_mfma_f32_16x16x32_bf16(af, bfr[ks], acc, 0, 0, 0);
      }
      float hb = hb1[col];
      float w2v = hw2[col];
#pragma unroll
      for (int r = 0; r < 4; ++r) {
        int row = mt * 16 + q * 4 + r;
        float y = ssp_f(acc[r] + hb) * w2v;
        y += __shfl_xor(y, 1);
        y += __shfl_xor(y, 2);
        y += __shfl_xor(y, 4);
        y += __shfl_xor(y, 8);
        if (r15 == 0 && row < NPG) atomicAdd(&shead[row], y);
      }
    }
  }
  __syncthreads();
  if (w == 0) {
    float v = (l6 < NPG) ? shead[l6] : 0.f;
#pragma unroll
    for (int off = 32; off; off >>= 1) v += __shfl_xor(v, off);
    if (l6 == 0) out[g] = v + (float)NPG * hb2[0];
  }
}

extern "C" void kernel_launch(void* const* d_in, const int* in_sizes, int n_in,
                              void* d_out, int out_size, void* d_ws, size_t ws_size,
                              hipStream_t stream) {
  const float* pos    = (const float*)d_in[0];
  const float* emb    = (const float*)d_in[1];
  const float* mlp_w1 = (const float*)d_in[2];
  const float* mlp_b1 = (const float*)d_in[3];
  const float* mlp_w2 = (const float*)d_in[4];
  const float* mlp_b2 = (const float*)d_in[5];
  const float* cf_w1  = (const float*)d_in[6];
  const float* cf_w2  = (const float*)d_in[7];
  const float* cf_b2  = (const float*)d_in[8];
  const float* lin_w  = (const float*)d_in[9];
  const float* lin_b  = (const float*)d_in[10];
  const float* hw1    = (const float*)d_in[11];
  const float* hb1    = (const float*)d_in[12];
  const float* hw2    = (const float*)d_in[13];
  const float* hb2    = (const float*)d_in[14];
  const int*   z      = (const int*)d_in[15];
  const int*   ei     = (const int*)d_in[17];

  char* wsb = (char*)d_ws;
  uint4*    ge     = (uint4*)wsb;                       // 500*680*16 = 5,440,000
  int*      gstart = (int*)(wsb + 5440000);             // 500*41*4   =    82,000
  unsigned* ptabg  = (unsigned*)(wsb + 5522000);        // 3*81*128*4 =   124,416
  ushort_t* wtb    = (ushort_t*)(wsb + 5646416);        // 10*16384*2 =   327,680
  size_t need = 5646416 + 327680;
  if (ws_size < need) return;

  k_pre<<<571, 512, 0, stream>>>(mlp_w1, mlp_b1, mlp_w2, mlp_b2, cf_w1, cf_w2, lin_w,
                                 hw1, pos, ei, ptabg, wtb, ge, gstart);
  k_mol<<<G_GRAPHS, 512, 0, stream>>>(emb, z, ge, gstart, ptabg, wtb,
                                      cf_b2, lin_b, hb1, hw2, hb2, (float*)d_out);
}